// Round 1
// baseline (1333221.875 us; speedup 1.0000x reference)
//
#include <hip/hip_runtime.h>

// ---------------------------------------------------------------------------
// fPEPS amplitude via boundary-MPS, chi=32. Metric ("left-Gram") formulation,
// f64 core with f32 bulk-tensor storage. Truncation = top eigvecs of M'^T G M'
// via in-LDS SHIFTED CholeskyQR2 subspace iteration (overflow-free, f64).
// Bottom & top chains fused per launch (blockIdx.z = sample*2+side).
// Lx=Ly=8, D=8, P=2, CHI=32.
// peps strides (f32): xi:65536 yi:8192 u:1024 d:128 l:16 r:2 s:1
// ---------------------------------------------------------------------------

__host__ __device__ static inline int imin_(int a,int b){return a<b?a:b;}

// per-JOB workspace (doubles). job = sample*2 + side (0=bottom,1=top)
static constexpr int SAMP_J = 1238016;   // 9.44 MB/job
static constexpr int O_CUR = 0;          // MPS, 8 sites x 8192 f64 [l][r][u]
static constexpr int O_NEW = 65536;
static constexpr int O_TF  = 131072;     // f32 T (524288 floats)
static constexpr int O_H2F = 393216;     // f32 H2 (524288 floats)
static constexpr int O_GSB = 655360;     // G slots (f64), +goff[y]
static constexpr int O_MP  = 992256;     // M' (l x ru) f64
static constexpr int O_H   = 1057792;    // H = G*M'
static constexpr int O_S   = 1123328;    // S_hat (ru x ru)
static constexpr int O_Y   = 1188864;    // subspace Y (256x64)
static constexpr int O_Y2  = 1205248;
static constexpr int O_C   = 1221632;    // C (l x keep)
static constexpr int O_V   = 1229824;    // V (ru x keep)

static const int goff[8] = {0,1,4097,69633,135169,200705,266241,331777};

// ---------------------------------------------------------------------------
__global__ void k_init_row(double* ws, const float* peps, const int* x, int s0){
  int z=blockIdx.z, y=blockIdx.x;
  int side=z&1, samp=z>>1;
  int xi = side?7:0;
  double* base = ws + (size_t)z*SAMP_J;
  double* cur = base + O_CUR + y*8192;
  int spin = x[(s0+samp)*64 + xi*8 + y];
  const float* pb = peps + (size_t)xi*65536 + (size_t)y*8192 + spin;
  int rd=(y<7)?8:1, ld=(y>0)?8:1;
  int ntot = ld*rd*8;
  for(int e=threadIdx.x; e<ntot; e+=blockDim.x){
    int u=e&7; int r=(e>>3)%rd; int l=e/(8*rd);
    float v = side ? pb[u*128 + l*16 + r*2] : pb[u*1024 + l*16 + r*2];
    cur[e]=(double)v;
  }
  if(y==0 && threadIdx.x==0) base[O_GSB]=1.0;   // G^(0)=[1]
}

// ---------------------------------------------------------------------------
// T[(x*Lp+lp)][(yb*Rp+rp)][u] = sum_p B[x][yb][p]*A[u,p,lp,rp]  (T stored f32)
__global__ __launch_bounds__(256)
void k_absorb(double* ws, const float* peps, const int* x, int s0,
              int xi_b, int xi_t, int y, int bl, int brdim){
  int z=blockIdx.z, yb=blockIdx.x;
  int side=z&1, samp=z>>1;
  int xi = side? xi_t : xi_b;
  int so = side? 128:1024, sc = side? 1024:128;
  double* base=ws+(size_t)z*SAMP_J;
  const double* B=base+O_CUR+y*8192;
  float* T=(float*)(base+O_TF);
  int spin=x[(s0+samp)*64+xi*8+y];
  const float* A=peps+(size_t)xi*65536+(size_t)y*8192+spin;
  int Lp=(y>0)?8:1, Rp=(y<7)?8:1;
  int rraw=brdim*Rp;
  __shared__ float As[4096];   // [u][p][lp][rp]
  __shared__ double Bs[256];   // [x][p]
  int nA=64*Lp*Rp;
  for(int e=threadIdx.x;e<nA;e+=256){
    int rp=e%Rp; int t=e/Rp; int lp=t%Lp; t/=Lp; int p=t&7; int u=t>>3;
    As[e]=A[u*so+p*sc+lp*16+rp*2];
  }
  for(int e=threadIdx.x;e<bl*8;e+=256)
    Bs[e]=B[((e>>3)*brdim+yb)*8+(e&7)];
  __syncthreads();
  int ntot=bl*Lp*Rp*8;
  for(int e=threadIdx.x;e<ntot;e+=256){
    int u=e&7; int t=e>>3; int rp=t%Rp; t/=Rp; int lp=t%Lp; int xx=t/Lp;
    double acc=0.0;
    #pragma unroll
    for(int p=0;p<8;p++) acc+=Bs[xx*8+p]*(double)As[((u*8+p)*Lp+lp)*Rp+rp];
    T[(size_t)((xx*Lp+lp)*rraw + yb*Rp+rp)*8 + u]=(float)acc;
  }
}

// ---------------------------------------------------------------------------
// H2(f32) = G(f64) * T(f32):  (ni x nk)(nk x nj)
__global__ void k_mmGT(double* ws, int Aoff, int Boff, int Coff, int ni, int nk, int nj){
  double* base=ws+(size_t)blockIdx.z*SAMP_J;
  const double* A=base+Aoff;
  const float* B=(const float*)(base+Boff);
  float* C=(float*)(base+Coff);
  __shared__ double As[16][17]; __shared__ float Bs[16][17];
  int tx=threadIdx.x, ty=threadIdx.y;
  int i0=blockIdx.x*16, j0=blockIdx.y*16;
  double acc=0.0;
  for(int k0=0;k0<nk;k0+=16){
    As[ty][tx]=(i0+ty<ni && k0+tx<nk)? A[(size_t)(i0+ty)*nk + k0+tx] : 0.0;
    Bs[ty][tx]=(k0+ty<nk && j0+tx<nj)? B[(size_t)(k0+ty)*nj + j0+tx] : 0.f;
    __syncthreads();
    #pragma unroll
    for(int t=0;t<16;t++) acc+=As[ty][t]*(double)Bs[t][tx];
    __syncthreads();
  }
  if(i0+ty<ni && j0+tx<nj) C[(size_t)(i0+ty)*nj + j0+tx]=(float)acc;
}

// f64 C = A*B and C = A^T*B (small, <=256^3)
__global__ void k_mm(double* ws, int Aoff, int Boff, int Coff, int ni, int nk, int nj){
  double* base=ws+(size_t)blockIdx.z*SAMP_J;
  const double* A=base+Aoff; const double* B=base+Boff; double* C=base+Coff;
  __shared__ double As[16][17], Bs[16][17];
  int tx=threadIdx.x, ty=threadIdx.y;
  int i0=blockIdx.x*16, j0=blockIdx.y*16;
  double acc=0.0;
  for(int k0=0;k0<nk;k0+=16){
    As[ty][tx]=(i0+ty<ni && k0+tx<nk)? A[(size_t)(i0+ty)*nk + k0+tx] : 0.0;
    Bs[ty][tx]=(k0+ty<nk && j0+tx<nj)? B[(size_t)(k0+ty)*nj + j0+tx] : 0.0;
    __syncthreads();
    #pragma unroll
    for(int t=0;t<16;t++) acc+=As[ty][t]*Bs[t][tx];
    __syncthreads();
  }
  if(i0+ty<ni && j0+tx<nj) C[(size_t)(i0+ty)*nj + j0+tx]=acc;
}
__global__ void k_mm_tn(double* ws, int Aoff, int Boff, int Coff, int ni, int nk, int nj){
  double* base=ws+(size_t)blockIdx.z*SAMP_J;
  const double* A=base+Aoff; const double* B=base+Boff; double* C=base+Coff;
  __shared__ double As[16][17], Bs[16][17];
  int tx=threadIdx.x, ty=threadIdx.y;
  int i0=blockIdx.x*16, j0=blockIdx.y*16;
  double acc=0.0;
  for(int k0=0;k0<nk;k0+=16){
    As[ty][tx]=(k0+ty<nk && i0+tx<ni)? A[(size_t)(k0+ty)*ni + i0+tx] : 0.0;
    Bs[ty][tx]=(k0+ty<nk && j0+tx<nj)? B[(size_t)(k0+ty)*nj + j0+tx] : 0.0;
    __syncthreads();
    #pragma unroll
    for(int t=0;t<16;t++) acc+=As[t][ty]*Bs[t][tx];
    __syncthreads();
  }
  if(i0+ty<ni && j0+tx<nj) C[(size_t)(i0+ty)*nj + j0+tx]=acc;
}

// ---------------------------------------------------------------------------
// G'(f64)[r][r'] = sum_{l,u} H2f[(l r u)] * Tf[(l r' u)]; upper + mirror
__global__ void k_gacc2(double* ws, int H2off, int Toff, int Goff, int ldim, int rdim){
  int bx=blockIdx.x, by=blockIdx.y;
  if(by<bx) return;
  double* base=ws+(size_t)blockIdx.z*SAMP_J;
  const float* H2=(const float*)(base+H2off);
  const float* T=(const float*)(base+Toff);
  double* G=base+Goff;
  __shared__ float As[16][17], Bs[16][17];
  int tx=threadIdx.x, ty=threadIdx.y;
  int r0=bx*16, r1=by*16;
  double acc=0.0;
  int ktot=ldim*8;
  for(int k0=0;k0<ktot;k0+=16){
    int kk=k0+ty; int l2=kk>>3; int u=kk&7;
    As[ty][tx]=(kk<ktot)? H2[((size_t)l2*rdim + r0+tx)*8 + u] : 0.f;
    Bs[ty][tx]=(kk<ktot)? T [((size_t)l2*rdim + r1+tx)*8 + u] : 0.f;
    __syncthreads();
    #pragma unroll
    for(int t=0;t<16;t++) acc+=(double)As[t][ty]*(double)Bs[t][tx];
    __syncthreads();
  }
  G[(size_t)(r0+ty)*rdim + r1+tx]=acc;
  if(by>bx) G[(size_t)(r1+tx)*rdim + r0+ty]=acc;
}

__global__ void k_gscale(double* ws, int Goff, int n){
  int tid=threadIdx.x;
  double* base=ws+(size_t)blockIdx.z*SAMP_J;
  double* G=base+Goff;
  __shared__ double red[256]; __shared__ double s_sc;
  double mx=0.0;
  for(int i=tid;i<n;i+=256) mx=fmax(mx,fabs(G[(size_t)i*n+i]));
  red[tid]=mx; __syncthreads();
  for(int w=128;w>0;w>>=1){ if(tid<w) red[tid]=fmax(red[tid],red[tid+w]); __syncthreads(); }
  if(tid==0) s_sc=(red[0]>0.0)?1.0/red[0]:1.0;
  __syncthreads();
  double sc=s_sc;
  for(int e=tid;e<n*n;e+=256) G[e]*=sc;
}

// ---------------------------------------------------------------------------
// M(f64)[li][(k*8+u)] = sum_r Tf[(li*rraw+r)*8+u] * C[r*keep+k]
__global__ __launch_bounds__(256)
void k_mp(double* ws, int Toff, int Coff, int Moff, int rraw, int keep){
  int li=blockIdx.x, tid=threadIdx.x;
  double* base=ws+(size_t)blockIdx.z*SAMP_J;
  const float* T=(const float*)(base+Toff) + (size_t)li*rraw*8;
  const double* Cc=base+Coff;
  double* M=base+Moff+(size_t)li*keep*8;
  __shared__ float Ts[2048];
  for(int e=tid;e<rraw*8;e+=256) Ts[e]=T[e];
  __syncthreads();
  for(int e=tid;e<keep*8;e+=256){
    int u=e&7, k=e>>3;
    double acc=0.0;
    for(int r=0;r<rraw;r++) acc+=(double)Ts[r*8+u]*Cc[(size_t)r*keep+k];
    M[k*8+u]=acc;
  }
}

__global__ void k_t2mp(double* ws, int n){
  double* base=ws+(size_t)blockIdx.z*SAMP_J;
  const float* T=(const float*)(base+O_TF);
  for(int e=blockIdx.x*blockDim.x+threadIdx.x;e<n;e+=gridDim.x*blockDim.x)
    base[O_MP+e]=(double)T[e];
}

// ---------------------------------------------------------------------------
__device__ void dev_jacobi(double* K, float* W, int q, int tid,
                           int* arrp, double* csC, double* csS, int* csP, int* csQ){
  int qpad=(q+1)&~1, npairs=qpad>>1;
  for(int e=tid;e<qpad;e+=256) arrp[e]=e;
  __syncthreads();
  for(int sweep=0;sweep<8;sweep++)
  for(int rnd=0;rnd<qpad-1;rnd++){
    if(tid<npairs){
      int p=arrp[tid], qq=arrp[qpad-1-tid];
      if(p>qq){int t=p;p=qq;qq=t;}
      double c=1.0,s2=0.0;
      if(qq<q && p!=qq){
        double apq=K[p*64+qq];
        double app=K[p*64+p], aqq=K[qq*64+qq];
        if(fabs(apq) > 1e-18*(fabs(app)+fabs(aqq))+1e-300){
          double tau=(aqq-app)/(2.0*apq);
          double t=(tau>=0.0?1.0:-1.0)/(fabs(tau)+sqrt(1.0+tau*tau));
          c=1.0/sqrt(1.0+t*t); s2=t*c;
        }
      } else { p=0; qq=0; }
      csP[tid]=p; csQ[tid]=qq; csC[tid]=c; csS[tid]=s2;
    }
    __syncthreads();
    int pr=tid>>3, lane=tid&7;
    if(pr<npairs){
      int p=csP[pr], qq=csQ[pr];
      if(p!=qq){
        double c=csC[pr], s2=csS[pr];
        for(int j=lane;j<q;j+=8){
          double kp=K[p*64+j], kq=K[qq*64+j];
          K[p*64+j]=c*kp-s2*kq; K[qq*64+j]=s2*kp+c*kq;
        }
      }
    }
    __syncthreads();
    if(pr<npairs){
      int p=csP[pr], qq=csQ[pr];
      if(p!=qq){
        double c=csC[pr], s2=csS[pr];
        float cf=(float)c, sf=(float)s2;
        for(int j=lane;j<q;j+=8){
          double kp=K[j*64+p], kq=K[j*64+qq];
          K[j*64+p]=c*kp-s2*kq; K[j*64+qq]=s2*kp+c*kq;
          float wp=W[j*64+p], wq=W[j*64+qq];
          W[j*64+p]=cf*wp-sf*wq; W[j*64+qq]=sf*wp+cf*wq;
        }
      }
    }
    __syncthreads();
    int myv=(tid<qpad)?arrp[tid]:-1;
    __syncthreads();
    if(tid>=1&&tid<qpad){ int dst=(tid==qpad-1)?1:tid+1; arrp[dst]=myv; }
    __syncthreads();
  }
}

__device__ void dev_select(const double* K, int q, int keep, int tid,
                           double* evals, int* idxs){
  if(tid==0){
    for(int a=0;a<q;a++){ evals[a]=K[a*64+a]; idxs[a]=a; }
    int lim=imin_(keep,q);
    for(int j=0;j<lim;j++){
      int bm=j;
      for(int a=j+1;a<q;a++) if(evals[idxs[a]]>evals[idxs[bm]]) bm=a;
      int t=idxs[j]; idxs[j]=idxs[bm]; idxs[bm]=t;
    }
  }
  __syncthreads();
}

// f64 CGS2 of V columns (n rows, keep cols, row-major stride keep)
__device__ void dev_orthV(double* V, int n, int keep, double* red){
  int tid=threadIdx.x;
  for(int j=0;j<keep;j++){
    double vj=(tid<n)? V[(size_t)tid*keep+j] : 0.0;
    for(int pass=0;pass<2;pass++){
      for(int t=0;t<j;t++){
        double vt=(tid<n)? V[(size_t)tid*keep+t] : 0.0;
        double p=vj*vt;
        for(int off=1;off<64;off<<=1) p+=__shfl_xor(p,off);
        if((tid&63)==0) red[tid>>6]=p;
        __syncthreads();
        double d=red[0]+red[1]+red[2]+red[3];
        vj-=d*vt;
        __syncthreads();
      }
    }
    double p=vj*vj;
    for(int off=1;off<64;off<<=1) p+=__shfl_xor(p,off);
    if((tid&63)==0) red[tid>>6]=p;
    __syncthreads();
    double nrm=red[0]+red[1]+red[2]+red[3];
    vj=vj/sqrt(fmax(nrm,1e-300));
    if(tid<n) V[(size_t)tid*keep+j]=vj;
    __syncthreads();
  }
}

// ---------------------------------------------------------------------------
// direct path (ru<=64): Jacobi on S; f64 orthonormalized V; ts=V^T, C=M'*V
__global__ __launch_bounds__(256)
void k_eig_direct(double* ws, int Soff, int MPoff, int l, int ru, int keep,
                  int newoff, int Coff){
  int tid=threadIdx.x;
  double* base=ws+(size_t)blockIdx.z*SAMP_J;
  const double* S=base+Soff;
  const double* MP=base+MPoff;
  double* C=base+Coff;
  double* NM=base+newoff;
  double* V=base+O_V;
  __shared__ double K[64*64];
  __shared__ float W[64*64];
  __shared__ int arrp[66];
  __shared__ double csC[32], csS[32];
  __shared__ int csP[32], csQ[32];
  __shared__ double evals[64]; __shared__ int idxs[64];
  __shared__ double red[4];
  int q=ru;
  for(int e=tid;e<q*q;e+=256){
    int a=e/q,b=e%q;
    K[a*64+b]=0.5*(S[(size_t)a*q+b]+S[(size_t)b*q+a]);
    W[a*64+b]=(a==b)?1.f:0.f;
  }
  __syncthreads();
  dev_jacobi(K,W,q,tid,arrp,csC,csS,csP,csQ);
  dev_select(K,q,keep,tid,evals,idxs);
  for(int e=tid;e<ru*keep;e+=256){
    int col=e/keep, j=e%keep;
    V[e]=(double)W[col*64+idxs[j]];
  }
  __syncthreads();
  dev_orthV(V,ru,keep,red);
  for(int e=tid;e<keep*ru;e+=256){
    int j=e/ru, col=e%ru;
    NM[e]=V[(size_t)col*keep+j];
  }
  for(int e=tid;e<l*keep;e+=256){
    int i=e/keep, j=e%keep;
    const double* Mi=MP+(size_t)i*ru;
    double acc=0.0;
    for(int c=0;c<ru;c++) acc+=Mi[c]*V[(size_t)c*keep+j];
    C[e]=acc;
  }
}

// ---------------------------------------------------------------------------
// Yout = sinv * S * Yin  (S 256x256 f64 global; Y 256x64 f64 global)
__device__ void dev_smul(const double* S, const double* Yin, double* Yout,
                         double* Yt, double sinv, int tid){
  for(int p=0;p<2;p++){
    double acc[32];
    #pragma unroll
    for(int j=0;j<32;j++) acc[j]=0.0;
    for(int cb=0;cb<16;cb++){
      __syncthreads();
      for(int e=tid;e<1024;e+=256) Yt[e]=Yin[cb*1024+e];
      __syncthreads();
      const double* Srow=S+(size_t)tid*256+cb*16;
      for(int c=0;c<16;c++){
        double sv=Srow[c];
        const double* Yr=Yt+c*64+p*32;
        #pragma unroll
        for(int j=0;j<32;j++) acc[j]+=sv*Yr[j];
      }
    }
    #pragma unroll
    for(int j=0;j<32;j++) Yout[(size_t)tid*64+p*32+j]=acc[j]*sinv;
  }
  __syncthreads();
}

// ---------------------------------------------------------------------------
// SHIFTED CholeskyQR pass on Yg (256 x ncols, row-major, f64 global).
// Gram+lam*I = R^T R (R upper in Kd, stride 64); then per-thread-row forward
// solve X R = Y (right-looking). Pivots >= lam/4 > 0: overflow-free in f64.
// Junk (rank-deficient) columns come out as bounded small-norm vectors.
__device__ void dev_cholqr(double* Yg, int ncols, double* Kd, double* Yt,
                           double* shv, int tid){
  int rpb=1024/ncols, nblk=256/rpb, n2=ncols*ncols;
  for(int e=tid;e<n2;e+=256) Kd[(e/ncols)*64+(e%ncols)]=0.0;
  for(int b=0;b<nblk;b++){
    __syncthreads();
    for(int e=tid;e<1024;e+=256) Yt[e]=Yg[b*1024+e];
    __syncthreads();
    for(int e=tid;e<n2;e+=256){
      int a=e/ncols, c=e%ncols;
      if(c>=a){
        double acc=0.0;
        for(int r=0;r<rpb;r++) acc+=Yt[r*ncols+a]*Yt[r*ncols+c];
        Kd[a*64+c]+=acc;
      }
    }
  }
  __syncthreads();
  if(tid==0){
    double tr=0.0;
    for(int j=0;j<ncols;j++) tr+=Kd[j*64+j];
    shv[0]=(tr/ncols)*1e-14+1e-290;
  }
  __syncthreads();
  double lam=shv[0];
  for(int i=tid;i<ncols;i+=256) Kd[i*64+i]+=lam;
  __syncthreads();
  // raw upper elimination; diag holds d_j >= lam*(1-eps)
  for(int j=0;j<ncols;j++){
    if(tid==0){
      double d=Kd[j*64+j];
      if(!(d>lam*0.25)) d=lam*0.25;
      Kd[j*64+j]=d; shv[1]=1.0/d;
    }
    __syncthreads();
    double invd=shv[1];
    int w=ncols-1-j;
    for(int e=tid;e<w*w;e+=256){
      int i2=j+1+e/w, k2=j+1+e%w;
      if(k2>=i2) Kd[i2*64+k2]-=Kd[j*64+i2]*Kd[j*64+k2]*invd;
    }
    __syncthreads();
  }
  // row-normalize -> R (upper, R_jj = sqrt(d_j))
  for(int i=tid;i<ncols;i+=256) Yt[i]=1.0/sqrt(Kd[i*64+i]);
  __syncthreads();
  for(int e=tid;e<n2;e+=256){
    int i=e/ncols, k=e%ncols;
    if(k>=i) Kd[i*64+k]*=Yt[i];
  }
  __syncthreads();
  // per-thread-row forward solve X R = Y (R broadcast from LDS)
  {
    double* row=Yg+(size_t)tid*ncols;
    for(int j=0;j<ncols;j++){
      double xv=row[j]/Kd[j*64+j];
      row[j]=xv;
      for(int k=j+1;k<ncols;k++) row[k]-=xv*Kd[j*64+k];
    }
  }
  __syncthreads();
}

// subspace path (ru==256): 20-step power iteration w/ shifted CholQR2 + Ritz
__global__ __launch_bounds__(256)
void k_eig_sub(double* ws, int Soff, int MPoff, int l, int keep,
               int newoff, int Coff){
  const int RU=256;
  int tid=threadIdx.x;
  double* base=ws+(size_t)blockIdx.z*SAMP_J;
  const double* S=base+Soff;
  const double* MP=base+MPoff;
  double* Ya=base+O_Y;
  double* Yb=base+O_Y2;
  double* V =base+O_V;
  double* C =base+Coff;
  double* NM=base+newoff;
  __shared__ double Kd[64*64];     // 32 KB
  __shared__ float  Wf[64*64];     // 16 KB (Jacobi eigvecs only)
  __shared__ double Yt[1024];      // 8 KB
  __shared__ double red[260];
  __shared__ int arrp[66];
  __shared__ double csC[32], csS[32];
  __shared__ int csP[32], csQ[32];
  __shared__ double evals[64]; __shared__ int idxs[64];

  // sinv = 1/max diag(S) (scale-invariant normalization)
  double mx=0.0;
  for(int i=tid;i<RU;i+=256) mx=fmax(mx,S[(size_t)i*RU+i]);
  red[tid]=mx; __syncthreads();
  for(int w=128;w>0;w>>=1){ if(tid<w) red[tid]=fmax(red[tid],red[tid+w]); __syncthreads(); }
  double sinv=(red[0]>0.0)?1.0/red[0]:1.0;
  __syncthreads();

  // Ya = sinv * S * Omega (deterministic +-1)
  for(int e=tid;e<RU*64;e+=256){
    int i=e>>6, j=e&63;
    const double* Si=S+(size_t)i*RU;
    double acc=0.0;
    for(int c2=0;c2<RU;c2++){
      unsigned h=(unsigned)(c2*1103515245u)^(unsigned)((j+1)*2654435761u);
      h^=h>>13; h*=0x9E3779B1u;
      acc += ((h>>16)&1u)? Si[c2] : -Si[c2];
    }
    Ya[e]=acc*sinv;
  }
  __syncthreads();
  dev_cholqr(Ya,64,Kd,Yt,red+256,tid);
  dev_cholqr(Ya,64,Kd,Yt,red+256,tid);
  for(int it=0;it<20;it++){
    dev_smul(S,Ya,Yb,Yt,sinv,tid);
    dev_cholqr(Yb,64,Kd,Yt,red+256,tid);
    dev_cholqr(Yb,64,Kd,Yt,red+256,tid);
    double* t=Ya; Ya=Yb; Yb=t;
  }
  dev_smul(S,Ya,Yb,Yt,sinv,tid);     // Yb = S*Ya (unorthogonalized)

  // Ritz: K = Ya^T Yb
  for(int e=tid;e<4096;e+=256) Kd[e]=0.0;
  for(int b=0;b<32;b++){
    __syncthreads();
    for(int e=tid;e<512;e+=256){ Yt[e]=Ya[b*512+e]; Yt[512+e]=Yb[b*512+e]; }
    __syncthreads();
    for(int i=0;i<16;i++){
      int e2=tid*16+i; int a=e2>>6, c=e2&63;
      double acc=Kd[e2];
      for(int r=0;r<8;r++) acc+=Yt[r*64+a]*Yt[512+r*64+c];
      Kd[e2]=acc;
    }
  }
  __syncthreads();
  for(int e=tid;e<4096;e+=256){
    int a=e>>6,c=e&63;
    if(a<c){ double m=0.5*(Kd[a*64+c]+Kd[c*64+a]); Kd[a*64+c]=m; Kd[c*64+a]=m; }
  }
  __syncthreads();
  for(int e=tid;e<4096;e+=256) Wf[e]=((e>>6)==(e&63))?1.f:0.f;
  __syncthreads();
  dev_jacobi(Kd,Wf,64,tid,arrp,csC,csS,csP,csQ);
  dev_select(Kd,64,keep,tid,evals,idxs);
  // V = Ya * W[:,sel]
  for(int e=tid;e<RU*keep;e+=256){
    int i=e/keep, j=e%keep; int vj=idxs[j];
    const double* Yr=Ya+(size_t)i*64;
    double acc=0.0;
    for(int t=0;t<64;t++) acc+=Yr[t]*(double)Wf[t*64+vj];
    V[e]=acc;
  }
  __syncthreads();
  dev_cholqr(V,keep,Kd,Yt,red+256,tid);   // f64 exact-projector fix
  for(int e=tid;e<keep*RU;e+=256){
    int j=e/RU, col=e%RU;
    NM[e]=V[(size_t)col*keep+j];
  }
  for(int e=tid;e<l*keep;e+=256){
    int i=e/keep, j=e%keep;
    const double* Mi=MP+(size_t)i*RU;
    double acc=0.0;
    for(int col=0;col<RU;col++) acc+=Mi[col]*V[(size_t)col*keep+j];
    C[e]=acc;
  }
}

// ---------------------------------------------------------------------------
__global__ void k_copy(double* ws){
  double* base=ws+(size_t)blockIdx.z*SAMP_J;
  for(int e=blockIdx.x*blockDim.x+threadIdx.x;e<65536;e+=gridDim.x*blockDim.x)
    base[O_CUR+e]=base[O_NEW+e];
}

// final chain contraction: bottom=job(2s), top=job(2s+1)
__global__ __launch_bounds__(256)
void k_final(double* ws, float* out, int s0){
  int z=blockIdx.z, tid=threadIdx.x;
  const double* bot=ws+(size_t)(2*z)*SAMP_J+O_CUR;
  const double* top=ws+(size_t)(2*z+1)*SAMP_J+O_CUR;
  __shared__ double v[1024], v2[1024];
  __shared__ float w[8192];
  const int Bf[9]={1,8,32,32,32,32,32,8,1};
  if(tid==0) v[0]=1.0;
  __syncthreads();
  for(int y=0;y<8;y++){
    int a=Bf[y], b=Bf[y+1];
    const double* By=bot+y*8192;
    const double* Ty=top+y*8192;
    for(int e=tid;e<a*b*8;e+=256){
      int k2=e&7; int bb=(e>>3)%b; int cc=e/(8*b);
      double acc=0.0;
      for(int aa=0;aa<a;aa++) acc+=v[aa*a+cc]*By[(aa*b+bb)*8+k2];
      w[(cc*b+bb)*8+k2]=(float)acc;
    }
    __syncthreads();
    for(int e=tid;e<b*b;e+=256){
      int dd=e%b; int bb=e/b;
      double acc=0.0;
      for(int cc=0;cc<a;cc++)
        for(int k2=0;k2<8;k2++)
          acc+=(double)w[(cc*b+bb)*8+k2]*Ty[(cc*b+dd)*8+k2];
      v2[bb*b+dd]=acc;
    }
    __syncthreads();
    for(int e=tid;e<b*b;e+=256) v[e]=v2[e];
    __syncthreads();
  }
  if(tid==0) out[s0+z]=(float)v[0];
}

// ---------------------------------------------------------------------------
static void run_compress_dual(double* ws, const float* peps, const int* x,
                              int s0, int ns, int xib, int xit, bool first,
                              hipStream_t stream){
  int njobs=2*ns;
  int Bin[9]; Bin[0]=1; Bin[8]=1;
  for(int i=1;i<8;i++) Bin[i]= first?8:((i==1||i==7)?8:32);
  int lraw[8], rraw[8];
  for(int y=0;y<8;y++){ lraw[y]=Bin[y]*((y>0)?8:1); rraw[y]=Bin[y+1]*((y<7)?8:1); }
  int kch[8];
  { int kp=1;
    for(int y=0;y<8;y++){ int n=(y<7)?Bin[y+1]*8:1; kch[y]=imin_(kp*8,n); kp=kch[y]; } }
  int keep[8];
  keep[7]=imin_(32, imin_(kch[6], 8));
  for(int y=6;y>=1;y--) keep[y]=imin_(32, imin_(kch[y-1], keep[y+1]*8));

  // forward: G^(1..7)
  for(int y=0;y<7;y++){
    k_absorb<<<dim3(Bin[y+1],1,njobs),256,0,stream>>>(ws,peps,x,s0,xib,xit,y,Bin[y],Bin[y+1]);
    int l=lraw[y], r8=rraw[y]*8;
    k_mmGT<<<dim3((l+15)/16,(r8+15)/16,njobs),dim3(16,16),0,stream>>>(
        ws,O_GSB+goff[y],O_TF,O_H2F,l,l,r8);
    k_gacc2<<<dim3(rraw[y]/16,rraw[y]/16,njobs),dim3(16,16),0,stream>>>(
        ws,O_H2F,O_TF,O_GSB+goff[y+1],l,rraw[y]);
    k_gscale<<<dim3(1,1,njobs),256,0,stream>>>(ws,O_GSB+goff[y+1],rraw[y]);
  }
  // backward
  for(int y=7;y>=1;y--){
    k_absorb<<<dim3(Bin[y+1],1,njobs),256,0,stream>>>(ws,peps,x,s0,xib,xit,y,Bin[y],Bin[y+1]);
    int ru=(y==7)?8:keep[y+1]*8;
    if(y==7) k_t2mp<<<dim3(2,1,njobs),256,0,stream>>>(ws,lraw[7]*8);
    else     k_mp<<<dim3(lraw[y],1,njobs),256,0,stream>>>(ws,O_TF,O_C,O_MP,rraw[y],keep[y+1]);
    int l=lraw[y];
    k_mm<<<dim3((l+15)/16,(ru+15)/16,njobs),dim3(16,16),0,stream>>>(
        ws,O_GSB+goff[y],O_MP,O_H,l,l,ru);
    k_mm_tn<<<dim3((ru+15)/16,(ru+15)/16,njobs),dim3(16,16),0,stream>>>(
        ws,O_MP,O_H,O_S,ru,l,ru);
    if(ru<=64)
      k_eig_direct<<<dim3(1,1,njobs),256,0,stream>>>(ws,O_S,O_MP,l,ru,keep[y],
                    O_NEW+y*8192,O_C);
    else
      k_eig_sub<<<dim3(1,1,njobs),256,0,stream>>>(ws,O_S,O_MP,l,keep[y],
                    O_NEW+y*8192,O_C);
  }
  // site 0: ts0 = T_0 * C_1
  k_absorb<<<dim3(Bin[1],1,njobs),256,0,stream>>>(ws,peps,x,s0,xib,xit,0,1,Bin[1]);
  k_mp<<<dim3(1,1,njobs),256,0,stream>>>(ws,O_TF,O_C,O_NEW+0,rraw[0],keep[1]);
  k_copy<<<dim3(32,1,njobs),256,0,stream>>>(ws);
}

extern "C" void kernel_launch(void* const* d_in, const int* in_sizes, int n_in,
                              void* d_out, int out_size, void* d_ws, size_t ws_size,
                              hipStream_t stream){
  const int*   x    = (const int*)d_in[0];     // (16,64) int32
  const float* peps = (const float*)d_in[1];   // (8,8,8,8,8,8,2) f32
  float* out = (float*)d_out;                  // 16 f32
  double* ws = (double*)d_ws;
  size_t samp_bytes = (size_t)2*SAMP_J*sizeof(double);   // 2 jobs/sample
  int max_chunk=(int)(ws_size/samp_bytes);
  if(max_chunk<1) max_chunk=1;
  if(max_chunk>16) max_chunk=16;
  for(int s0=0;s0<16;s0+=max_chunk){
    int ns=imin_(max_chunk,16-s0);
    int njobs=2*ns;
    k_init_row<<<dim3(8,1,njobs),64,0,stream>>>(ws,peps,x,s0);
    run_compress_dual(ws,peps,x,s0,ns,1,6,true ,stream);
    run_compress_dual(ws,peps,x,s0,ns,2,5,false,stream);
    run_compress_dual(ws,peps,x,s0,ns,3,4,false,stream);
    k_final<<<dim3(1,1,ns),256,0,stream>>>(ws,out,s0);
  }
}

// Round 2
// 810619.189 us; speedup vs baseline: 1.6447x; 1.6447x over previous
//
#include <hip/hip_runtime.h>

// ---------------------------------------------------------------------------
// fPEPS amplitude via boundary-MPS, chi=32. Metric ("left-Gram") formulation,
// f64 core with f32 bulk-tensor storage. Truncation = top eigvecs of M'^T G M'
// via in-LDS SHIFTED CholeskyQR2 subspace iteration (overflow-free, f64).
// Bottom & top chains fused per launch (blockIdx.z = sample*2+side).
// Lx=Ly=8, D=8, P=2, CHI=32.
// peps strides (f32): xi:65536 yi:8192 u:1024 d:128 l:16 r:2 s:1
//
// R1 change: dev_cholqr solve -> in-LDS Rinv + staged GEMM (was uncoalesced
// global RMW); elimination 1 barrier/col; dev_smul single-pass (64 acc).
// ---------------------------------------------------------------------------

__host__ __device__ static inline int imin_(int a,int b){return a<b?a:b;}

// per-JOB workspace (doubles). job = sample*2 + side (0=bottom,1=top)
static constexpr int SAMP_J = 1238016;   // 9.44 MB/job
static constexpr int O_CUR = 0;          // MPS, 8 sites x 8192 f64 [l][r][u]
static constexpr int O_NEW = 65536;
static constexpr int O_TF  = 131072;     // f32 T (524288 floats)
static constexpr int O_H2F = 393216;     // f32 H2 (524288 floats)
static constexpr int O_GSB = 655360;     // G slots (f64), +goff[y]
static constexpr int O_MP  = 992256;     // M' (l x ru) f64
static constexpr int O_H   = 1057792;    // H = G*M'
static constexpr int O_S   = 1123328;    // S_hat (ru x ru)
static constexpr int O_Y   = 1188864;    // subspace Y (256x64)
static constexpr int O_Y2  = 1205248;
static constexpr int O_C   = 1221632;    // C (l x keep)
static constexpr int O_V   = 1229824;    // V (ru x keep)

static const int goff[8] = {0,1,4097,69633,135169,200705,266241,331777};

// ---------------------------------------------------------------------------
__global__ void k_init_row(double* ws, const float* peps, const int* x, int s0){
  int z=blockIdx.z, y=blockIdx.x;
  int side=z&1, samp=z>>1;
  int xi = side?7:0;
  double* base = ws + (size_t)z*SAMP_J;
  double* cur = base + O_CUR + y*8192;
  int spin = x[(s0+samp)*64 + xi*8 + y];
  const float* pb = peps + (size_t)xi*65536 + (size_t)y*8192 + spin;
  int rd=(y<7)?8:1, ld=(y>0)?8:1;
  int ntot = ld*rd*8;
  for(int e=threadIdx.x; e<ntot; e+=blockDim.x){
    int u=e&7; int r=(e>>3)%rd; int l=e/(8*rd);
    float v = side ? pb[u*128 + l*16 + r*2] : pb[u*1024 + l*16 + r*2];
    cur[e]=(double)v;
  }
  if(y==0 && threadIdx.x==0) base[O_GSB]=1.0;   // G^(0)=[1]
}

// ---------------------------------------------------------------------------
// T[(x*Lp+lp)][(yb*Rp+rp)][u] = sum_p B[x][yb][p]*A[u,p,lp,rp]  (T stored f32)
__global__ __launch_bounds__(256)
void k_absorb(double* ws, const float* peps, const int* x, int s0,
              int xi_b, int xi_t, int y, int bl, int brdim){
  int z=blockIdx.z, yb=blockIdx.x;
  int side=z&1, samp=z>>1;
  int xi = side? xi_t : xi_b;
  int so = side? 128:1024, sc = side? 1024:128;
  double* base=ws+(size_t)z*SAMP_J;
  const double* B=base+O_CUR+y*8192;
  float* T=(float*)(base+O_TF);
  int spin=x[(s0+samp)*64+xi*8+y];
  const float* A=peps+(size_t)xi*65536+(size_t)y*8192+spin;
  int Lp=(y>0)?8:1, Rp=(y<7)?8:1;
  int rraw=brdim*Rp;
  __shared__ float As[4096];   // [u][p][lp][rp]
  __shared__ double Bs[256];   // [x][p]
  int nA=64*Lp*Rp;
  for(int e=threadIdx.x;e<nA;e+=256){
    int rp=e%Rp; int t=e/Rp; int lp=t%Lp; t/=Lp; int p=t&7; int u=t>>3;
    As[e]=A[u*so+p*sc+lp*16+rp*2];
  }
  for(int e=threadIdx.x;e<bl*8;e+=256)
    Bs[e]=B[((e>>3)*brdim+yb)*8+(e&7)];
  __syncthreads();
  int ntot=bl*Lp*Rp*8;
  for(int e=threadIdx.x;e<ntot;e+=256){
    int u=e&7; int t=e>>3; int rp=t%Rp; t/=Rp; int lp=t%Lp; int xx=t/Lp;
    double acc=0.0;
    #pragma unroll
    for(int p=0;p<8;p++) acc+=Bs[xx*8+p]*(double)As[((u*8+p)*Lp+lp)*Rp+rp];
    T[(size_t)((xx*Lp+lp)*rraw + yb*Rp+rp)*8 + u]=(float)acc;
  }
}

// ---------------------------------------------------------------------------
// H2(f32) = G(f64) * T(f32):  (ni x nk)(nk x nj)
__global__ void k_mmGT(double* ws, int Aoff, int Boff, int Coff, int ni, int nk, int nj){
  double* base=ws+(size_t)blockIdx.z*SAMP_J;
  const double* A=base+Aoff;
  const float* B=(const float*)(base+Boff);
  float* C=(float*)(base+Coff);
  __shared__ double As[16][17]; __shared__ float Bs[16][17];
  int tx=threadIdx.x, ty=threadIdx.y;
  int i0=blockIdx.x*16, j0=blockIdx.y*16;
  double acc=0.0;
  for(int k0=0;k0<nk;k0+=16){
    As[ty][tx]=(i0+ty<ni && k0+tx<nk)? A[(size_t)(i0+ty)*nk + k0+tx] : 0.0;
    Bs[ty][tx]=(k0+ty<nk && j0+tx<nj)? B[(size_t)(k0+ty)*nj + j0+tx] : 0.f;
    __syncthreads();
    #pragma unroll
    for(int t=0;t<16;t++) acc+=As[ty][t]*(double)Bs[t][tx];
    __syncthreads();
  }
  if(i0+ty<ni && j0+tx<nj) C[(size_t)(i0+ty)*nj + j0+tx]=(float)acc;
}

// f64 C = A*B and C = A^T*B (small, <=256^3)
__global__ void k_mm(double* ws, int Aoff, int Boff, int Coff, int ni, int nk, int nj){
  double* base=ws+(size_t)blockIdx.z*SAMP_J;
  const double* A=base+Aoff; const double* B=base+Boff; double* C=base+Coff;
  __shared__ double As[16][17], Bs[16][17];
  int tx=threadIdx.x, ty=threadIdx.y;
  int i0=blockIdx.x*16, j0=blockIdx.y*16;
  double acc=0.0;
  for(int k0=0;k0<nk;k0+=16){
    As[ty][tx]=(i0+ty<ni && k0+tx<nk)? A[(size_t)(i0+ty)*nk + k0+tx] : 0.0;
    Bs[ty][tx]=(k0+ty<nk && j0+tx<nj)? B[(size_t)(k0+ty)*nj + j0+tx] : 0.0;
    __syncthreads();
    #pragma unroll
    for(int t=0;t<16;t++) acc+=As[ty][t]*Bs[t][tx];
    __syncthreads();
  }
  if(i0+ty<ni && j0+tx<nj) C[(size_t)(i0+ty)*nj + j0+tx]=acc;
}
__global__ void k_mm_tn(double* ws, int Aoff, int Boff, int Coff, int ni, int nk, int nj){
  double* base=ws+(size_t)blockIdx.z*SAMP_J;
  const double* A=base+Aoff; const double* B=base+Boff; double* C=base+Coff;
  __shared__ double As[16][17], Bs[16][17];
  int tx=threadIdx.x, ty=threadIdx.y;
  int i0=blockIdx.x*16, j0=blockIdx.y*16;
  double acc=0.0;
  for(int k0=0;k0<nk;k0+=16){
    As[ty][tx]=(k0+ty<nk && i0+tx<ni)? A[(size_t)(k0+ty)*ni + i0+tx] : 0.0;
    Bs[ty][tx]=(k0+ty<nk && j0+tx<nj)? B[(size_t)(k0+ty)*nj + j0+tx] : 0.0;
    __syncthreads();
    #pragma unroll
    for(int t=0;t<16;t++) acc+=As[t][ty]*Bs[t][tx];
    __syncthreads();
  }
  if(i0+ty<ni && j0+tx<nj) C[(size_t)(i0+ty)*nj + j0+tx]=acc;
}

// ---------------------------------------------------------------------------
// G'(f64)[r][r'] = sum_{l,u} H2f[(l r u)] * Tf[(l r' u)]; upper + mirror
__global__ void k_gacc2(double* ws, int H2off, int Toff, int Goff, int ldim, int rdim){
  int bx=blockIdx.x, by=blockIdx.y;
  if(by<bx) return;
  double* base=ws+(size_t)blockIdx.z*SAMP_J;
  const float* H2=(const float*)(base+H2off);
  const float* T=(const float*)(base+Toff);
  double* G=base+Goff;
  __shared__ float As[16][17], Bs[16][17];
  int tx=threadIdx.x, ty=threadIdx.y;
  int r0=bx*16, r1=by*16;
  double acc=0.0;
  int ktot=ldim*8;
  for(int k0=0;k0<ktot;k0+=16){
    int kk=k0+ty; int l2=kk>>3; int u=kk&7;
    As[ty][tx]=(kk<ktot)? H2[((size_t)l2*rdim + r0+tx)*8 + u] : 0.f;
    Bs[ty][tx]=(kk<ktot)? T [((size_t)l2*rdim + r1+tx)*8 + u] : 0.f;
    __syncthreads();
    #pragma unroll
    for(int t=0;t<16;t++) acc+=(double)As[t][ty]*(double)Bs[t][tx];
    __syncthreads();
  }
  G[(size_t)(r0+ty)*rdim + r1+tx]=acc;
  if(by>bx) G[(size_t)(r1+tx)*rdim + r0+ty]=acc;
}

__global__ void k_gscale(double* ws, int Goff, int n){
  int tid=threadIdx.x;
  double* base=ws+(size_t)blockIdx.z*SAMP_J;
  double* G=base+Goff;
  __shared__ double red[256]; __shared__ double s_sc;
  double mx=0.0;
  for(int i=tid;i<n;i+=256) mx=fmax(mx,fabs(G[(size_t)i*n+i]));
  red[tid]=mx; __syncthreads();
  for(int w=128;w>0;w>>=1){ if(tid<w) red[tid]=fmax(red[tid],red[tid+w]); __syncthreads(); }
  if(tid==0) s_sc=(red[0]>0.0)?1.0/red[0]:1.0;
  __syncthreads();
  double sc=s_sc;
  for(int e=tid;e<n*n;e+=256) G[e]*=sc;
}

// ---------------------------------------------------------------------------
// M(f64)[li][(k*8+u)] = sum_r Tf[(li*rraw+r)*8+u] * C[r*keep+k]
__global__ __launch_bounds__(256)
void k_mp(double* ws, int Toff, int Coff, int Moff, int rraw, int keep){
  int li=blockIdx.x, tid=threadIdx.x;
  double* base=ws+(size_t)blockIdx.z*SAMP_J;
  const float* T=(const float*)(base+Toff) + (size_t)li*rraw*8;
  const double* Cc=base+Coff;
  double* M=base+Moff+(size_t)li*keep*8;
  __shared__ float Ts[2048];
  for(int e=tid;e<rraw*8;e+=256) Ts[e]=T[e];
  __syncthreads();
  for(int e=tid;e<keep*8;e+=256){
    int u=e&7, k=e>>3;
    double acc=0.0;
    for(int r=0;r<rraw;r++) acc+=(double)Ts[r*8+u]*Cc[(size_t)r*keep+k];
    M[k*8+u]=acc;
  }
}

__global__ void k_t2mp(double* ws, int n){
  double* base=ws+(size_t)blockIdx.z*SAMP_J;
  const float* T=(const float*)(base+O_TF);
  for(int e=blockIdx.x*blockDim.x+threadIdx.x;e<n;e+=gridDim.x*blockDim.x)
    base[O_MP+e]=(double)T[e];
}

// ---------------------------------------------------------------------------
__device__ void dev_jacobi(double* K, float* W, int q, int tid,
                           int* arrp, double* csC, double* csS, int* csP, int* csQ){
  int qpad=(q+1)&~1, npairs=qpad>>1;
  for(int e=tid;e<qpad;e+=256) arrp[e]=e;
  __syncthreads();
  for(int sweep=0;sweep<8;sweep++)
  for(int rnd=0;rnd<qpad-1;rnd++){
    if(tid<npairs){
      int p=arrp[tid], qq=arrp[qpad-1-tid];
      if(p>qq){int t=p;p=qq;qq=t;}
      double c=1.0,s2=0.0;
      if(qq<q && p!=qq){
        double apq=K[p*64+qq];
        double app=K[p*64+p], aqq=K[qq*64+qq];
        if(fabs(apq) > 1e-18*(fabs(app)+fabs(aqq))+1e-300){
          double tau=(aqq-app)/(2.0*apq);
          double t=(tau>=0.0?1.0:-1.0)/(fabs(tau)+sqrt(1.0+tau*tau));
          c=1.0/sqrt(1.0+t*t); s2=t*c;
        }
      } else { p=0; qq=0; }
      csP[tid]=p; csQ[tid]=qq; csC[tid]=c; csS[tid]=s2;
    }
    __syncthreads();
    int pr=tid>>3, lane=tid&7;
    if(pr<npairs){
      int p=csP[pr], qq=csQ[pr];
      if(p!=qq){
        double c=csC[pr], s2=csS[pr];
        for(int j=lane;j<q;j+=8){
          double kp=K[p*64+j], kq=K[qq*64+j];
          K[p*64+j]=c*kp-s2*kq; K[qq*64+j]=s2*kp+c*kq;
        }
      }
    }
    __syncthreads();
    if(pr<npairs){
      int p=csP[pr], qq=csQ[pr];
      if(p!=qq){
        double c=csC[pr], s2=csS[pr];
        float cf=(float)c, sf=(float)s2;
        for(int j=lane;j<q;j+=8){
          double kp=K[j*64+p], kq=K[j*64+qq];
          K[j*64+p]=c*kp-s2*kq; K[j*64+qq]=s2*kp+c*kq;
          float wp=W[j*64+p], wq=W[j*64+qq];
          W[j*64+p]=cf*wp-sf*wq; W[j*64+qq]=sf*wp+cf*wq;
        }
      }
    }
    __syncthreads();
    int myv=(tid<qpad)?arrp[tid]:-1;
    __syncthreads();
    if(tid>=1&&tid<qpad){ int dst=(tid==qpad-1)?1:tid+1; arrp[dst]=myv; }
    __syncthreads();
  }
}

__device__ void dev_select(const double* K, int q, int keep, int tid,
                           double* evals, int* idxs){
  if(tid==0){
    for(int a=0;a<q;a++){ evals[a]=K[a*64+a]; idxs[a]=a; }
    int lim=imin_(keep,q);
    for(int j=0;j<lim;j++){
      int bm=j;
      for(int a=j+1;a<q;a++) if(evals[idxs[a]]>evals[idxs[bm]]) bm=a;
      int t=idxs[j]; idxs[j]=idxs[bm]; idxs[bm]=t;
    }
  }
  __syncthreads();
}

// f64 CGS2 of V columns (n rows, keep cols, row-major stride keep)
__device__ void dev_orthV(double* V, int n, int keep, double* red){
  int tid=threadIdx.x;
  for(int j=0;j<keep;j++){
    double vj=(tid<n)? V[(size_t)tid*keep+j] : 0.0;
    for(int pass=0;pass<2;pass++){
      for(int t=0;t<j;t++){
        double vt=(tid<n)? V[(size_t)tid*keep+t] : 0.0;
        double p=vj*vt;
        for(int off=1;off<64;off<<=1) p+=__shfl_xor(p,off);
        if((tid&63)==0) red[tid>>6]=p;
        __syncthreads();
        double d=red[0]+red[1]+red[2]+red[3];
        vj-=d*vt;
        __syncthreads();
      }
    }
    double p=vj*vj;
    for(int off=1;off<64;off<<=1) p+=__shfl_xor(p,off);
    if((tid&63)==0) red[tid>>6]=p;
    __syncthreads();
    double nrm=red[0]+red[1]+red[2]+red[3];
    vj=vj/sqrt(fmax(nrm,1e-300));
    if(tid<n) V[(size_t)tid*keep+j]=vj;
    __syncthreads();
  }
}

// ---------------------------------------------------------------------------
// direct path (ru<=64): Jacobi on S; f64 orthonormalized V; ts=V^T, C=M'*V
__global__ __launch_bounds__(256)
void k_eig_direct(double* ws, int Soff, int MPoff, int l, int ru, int keep,
                  int newoff, int Coff){
  int tid=threadIdx.x;
  double* base=ws+(size_t)blockIdx.z*SAMP_J;
  const double* S=base+Soff;
  const double* MP=base+MPoff;
  double* C=base+Coff;
  double* NM=base+newoff;
  double* V=base+O_V;
  __shared__ double K[64*64];
  __shared__ float W[64*64];
  __shared__ int arrp[66];
  __shared__ double csC[32], csS[32];
  __shared__ int csP[32], csQ[32];
  __shared__ double evals[64]; __shared__ int idxs[64];
  __shared__ double red[4];
  int q=ru;
  for(int e=tid;e<q*q;e+=256){
    int a=e/q,b=e%q;
    K[a*64+b]=0.5*(S[(size_t)a*q+b]+S[(size_t)b*q+a]);
    W[a*64+b]=(a==b)?1.f:0.f;
  }
  __syncthreads();
  dev_jacobi(K,W,q,tid,arrp,csC,csS,csP,csQ);
  dev_select(K,q,keep,tid,evals,idxs);
  for(int e=tid;e<ru*keep;e+=256){
    int col=e/keep, j=e%keep;
    V[e]=(double)W[col*64+idxs[j]];
  }
  __syncthreads();
  dev_orthV(V,ru,keep,red);
  for(int e=tid;e<keep*ru;e+=256){
    int j=e/ru, col=e%ru;
    NM[e]=V[(size_t)col*keep+j];
  }
  for(int e=tid;e<l*keep;e+=256){
    int i=e/keep, j=e%keep;
    const double* Mi=MP+(size_t)i*ru;
    double acc=0.0;
    for(int c=0;c<ru;c++) acc+=Mi[c]*V[(size_t)c*keep+j];
    C[e]=acc;
  }
}

// ---------------------------------------------------------------------------
// Yout = sinv * S * Yin  (S 256x256 f64 global; Y 256x64 f64 global)
// single pass, 64 f64 accumulators (needs launch_bounds(256,1): no spill)
__device__ void dev_smul(const double* S, const double* Yin, double* Yout,
                         double* Yt, double sinv, int tid){
  double acc[64];
  #pragma unroll
  for(int j=0;j<64;j++) acc[j]=0.0;
  for(int cb=0;cb<16;cb++){
    __syncthreads();
    for(int e=tid;e<1024;e+=256) Yt[e]=Yin[cb*1024+e];
    __syncthreads();
    const double* Srow=S+(size_t)tid*256+cb*16;
    for(int c=0;c<16;c++){
      double sv=Srow[c];
      const double* Yr=Yt+c*64;
      #pragma unroll
      for(int j=0;j<64;j++) acc[j]+=sv*Yr[j];
    }
  }
  #pragma unroll
  for(int j=0;j<64;j++) Yout[(size_t)tid*64+j]=acc[j]*sinv;
  __syncthreads();
}

// ---------------------------------------------------------------------------
// SHIFTED CholeskyQR pass on Yg (256 x ncols, row-major, f64 global).
// Gram+lam*I = R^T R (R upper in Kd, stride 64). Then Ri = R^{-1} built in
// LDS (one column per lane, back-substitution), and X = Y * Ri applied as a
// staged GEMM: coalesced global traffic, LDS-resident inner loops.
// Pivots >= lam/4 > 0: overflow-free in f64. Junk (rank-deficient) columns
// come out as bounded small-norm vectors.
__device__ void dev_cholqr(double* Yg, int ncols, double* Kd, double* Yt,
                           double* Ri, double* shv, int tid){
  int rpb=1024/ncols, nblk=256/rpb, n2=ncols*ncols;
  for(int e=tid;e<n2;e+=256) Kd[(e/ncols)*64+(e%ncols)]=0.0;
  for(int b=0;b<nblk;b++){
    __syncthreads();
    for(int e=tid;e<1024;e+=256) Yt[e]=Yg[b*1024+e];
    __syncthreads();
    for(int e=tid;e<n2;e+=256){
      int a=e/ncols, c=e%ncols;
      if(c>=a){
        double acc=0.0;
        for(int r=0;r<rpb;r++) acc+=Yt[r*ncols+a]*Yt[r*ncols+c];
        Kd[a*64+c]+=acc;
      }
    }
  }
  __syncthreads();
  if(tid==0){
    double tr=0.0;
    for(int j=0;j<ncols;j++) tr+=Kd[j*64+j];
    shv[0]=(tr/ncols)*1e-14+1e-290;
  }
  __syncthreads();
  double lam=shv[0];
  for(int i=tid;i<ncols;i+=256) Kd[i*64+i]+=lam;
  __syncthreads();
  // raw upper elimination; diag holds d_j >= lam/4. One barrier per column:
  // the pivot clamp is computed redundantly per-thread (idempotent), tid 0
  // persists it for the normalization phase.
  for(int j=0;j<ncols;j++){
    double d=Kd[j*64+j];
    if(!(d>lam*0.25)) d=lam*0.25;
    double invd=1.0/d;
    if(tid==0) Kd[j*64+j]=d;
    int w=ncols-1-j;
    for(int e=tid;e<w*w;e+=256){
      int i2=j+1+e/w, k2=j+1+e%w;
      if(k2>=i2) Kd[i2*64+k2]-=Kd[j*64+i2]*Kd[j*64+k2]*invd;
    }
    __syncthreads();
  }
  // row-normalize -> R (upper, R_jj = sqrt(d_j))
  for(int i=tid;i<ncols;i+=256) Yt[i]=1.0/sqrt(Kd[i*64+i]);
  __syncthreads();
  for(int e=tid;e<n2;e+=256){
    int i=e/ncols, k=e%ncols;
    if(k>=i) Kd[i*64+k]*=Yt[i];
  }
  __syncthreads();
  // Ri = R^{-1} (upper, stride 66). Column j by lane j: back-substitution.
  if(tid<ncols){
    int j=tid;
    Ri[j*66+j]=1.0/Kd[j*64+j];
    for(int i=j-1;i>=0;i--){
      double s=0.0;
      for(int k=i+1;k<=j;k++) s+=Kd[i*64+k]*Ri[k*66+j];
      Ri[i*66+j]=-s/Kd[i*64+i];
    }
  }
  __syncthreads();
  // X = Y * Ri, staged through Yt per row-block. thread: j = tid%ncols
  // (coalesced stores), rg = tid/ncols covering 4 rows of the block.
  {
    int j=tid%ncols, rg=tid/ncols;
    for(int b=0;b<nblk;b++){
      for(int e=tid;e<1024;e+=256) Yt[e]=Yg[b*1024+e];
      __syncthreads();
      double xr[4];
      #pragma unroll
      for(int r4=0;r4<4;r4++){
        int r=rg*4+r4;
        double acc=0.0;
        for(int k=0;k<=j;k++) acc+=Yt[r*ncols+k]*Ri[k*66+j];
        xr[r4]=acc;
      }
      __syncthreads();
      #pragma unroll
      for(int r4=0;r4<4;r4++){
        int r=rg*4+r4;
        Yg[(size_t)b*1024 + r*ncols + j]=xr[r4];
      }
    }
  }
  __syncthreads();
}

// subspace path (ru==256): 20-step power iteration w/ shifted CholQR2 + Ritz
__global__ __launch_bounds__(256,1)
void k_eig_sub(double* ws, int Soff, int MPoff, int l, int keep,
               int newoff, int Coff){
  const int RU=256;
  int tid=threadIdx.x;
  double* base=ws+(size_t)blockIdx.z*SAMP_J;
  const double* S=base+Soff;
  const double* MP=base+MPoff;
  double* Ya=base+O_Y;
  double* Yb=base+O_Y2;
  double* V =base+O_V;
  double* C =base+Coff;
  double* NM=base+newoff;
  __shared__ double Kd[64*64];     // 32 KB
  __shared__ double Ri[64*66];     // 33 KB (R^{-1} for cholqr)
  __shared__ float  Wf[64*64];     // 16 KB (Jacobi eigvecs only)
  __shared__ double Yt[1024];      // 8 KB
  __shared__ double red[260];
  __shared__ int arrp[66];
  __shared__ double csC[32], csS[32];
  __shared__ int csP[32], csQ[32];
  __shared__ double evals[64]; __shared__ int idxs[64];

  // sinv = 1/max diag(S) (scale-invariant normalization)
  double mx=0.0;
  for(int i=tid;i<RU;i+=256) mx=fmax(mx,S[(size_t)i*RU+i]);
  red[tid]=mx; __syncthreads();
  for(int w=128;w>0;w>>=1){ if(tid<w) red[tid]=fmax(red[tid],red[tid+w]); __syncthreads(); }
  double sinv=(red[0]>0.0)?1.0/red[0]:1.0;
  __syncthreads();

  // Ya = sinv * S * Omega (deterministic +-1)
  for(int e=tid;e<RU*64;e+=256){
    int i=e>>6, j=e&63;
    const double* Si=S+(size_t)i*RU;
    double acc=0.0;
    for(int c2=0;c2<RU;c2++){
      unsigned h=(unsigned)(c2*1103515245u)^(unsigned)((j+1)*2654435761u);
      h^=h>>13; h*=0x9E3779B1u;
      acc += ((h>>16)&1u)? Si[c2] : -Si[c2];
    }
    Ya[e]=acc*sinv;
  }
  __syncthreads();
  dev_cholqr(Ya,64,Kd,Yt,Ri,red+256,tid);
  dev_cholqr(Ya,64,Kd,Yt,Ri,red+256,tid);
  for(int it=0;it<20;it++){
    dev_smul(S,Ya,Yb,Yt,sinv,tid);
    dev_cholqr(Yb,64,Kd,Yt,Ri,red+256,tid);
    dev_cholqr(Yb,64,Kd,Yt,Ri,red+256,tid);
    double* t=Ya; Ya=Yb; Yb=t;
  }
  dev_smul(S,Ya,Yb,Yt,sinv,tid);     // Yb = S*Ya (unorthogonalized)

  // Ritz: K = Ya^T Yb
  for(int e=tid;e<4096;e+=256) Kd[e]=0.0;
  for(int b=0;b<32;b++){
    __syncthreads();
    for(int e=tid;e<512;e+=256){ Yt[e]=Ya[b*512+e]; Yt[512+e]=Yb[b*512+e]; }
    __syncthreads();
    for(int i=0;i<16;i++){
      int e2=tid*16+i; int a=e2>>6, c=e2&63;
      double acc=Kd[e2];
      for(int r=0;r<8;r++) acc+=Yt[r*64+a]*Yt[512+r*64+c];
      Kd[e2]=acc;
    }
  }
  __syncthreads();
  for(int e=tid;e<4096;e+=256){
    int a=e>>6,c=e&63;
    if(a<c){ double m=0.5*(Kd[a*64+c]+Kd[c*64+a]); Kd[a*64+c]=m; Kd[c*64+a]=m; }
  }
  __syncthreads();
  for(int e=tid;e<4096;e+=256) Wf[e]=((e>>6)==(e&63))?1.f:0.f;
  __syncthreads();
  dev_jacobi(Kd,Wf,64,tid,arrp,csC,csS,csP,csQ);
  dev_select(Kd,64,keep,tid,evals,idxs);
  // V = Ya * W[:,sel]
  for(int e=tid;e<RU*keep;e+=256){
    int i=e/keep, j=e%keep; int vj=idxs[j];
    const double* Yr=Ya+(size_t)i*64;
    double acc=0.0;
    for(int t=0;t<64;t++) acc+=Yr[t]*(double)Wf[t*64+vj];
    V[e]=acc;
  }
  __syncthreads();
  dev_cholqr(V,keep,Kd,Yt,Ri,red+256,tid);   // f64 exact-projector fix
  for(int e=tid;e<keep*RU;e+=256){
    int j=e/RU, col=e%RU;
    NM[e]=V[(size_t)col*keep+j];
  }
  for(int e=tid;e<l*keep;e+=256){
    int i=e/keep, j=e%keep;
    const double* Mi=MP+(size_t)i*RU;
    double acc=0.0;
    for(int col=0;col<RU;col++) acc+=Mi[col]*V[(size_t)col*keep+j];
    C[e]=acc;
  }
}

// ---------------------------------------------------------------------------
__global__ void k_copy(double* ws){
  double* base=ws+(size_t)blockIdx.z*SAMP_J;
  for(int e=blockIdx.x*blockDim.x+threadIdx.x;e<65536;e+=gridDim.x*blockDim.x)
    base[O_CUR+e]=base[O_NEW+e];
}

// final chain contraction: bottom=job(2s), top=job(2s+1)
__global__ __launch_bounds__(256)
void k_final(double* ws, float* out, int s0){
  int z=blockIdx.z, tid=threadIdx.x;
  const double* bot=ws+(size_t)(2*z)*SAMP_J+O_CUR;
  const double* top=ws+(size_t)(2*z+1)*SAMP_J+O_CUR;
  __shared__ double v[1024], v2[1024];
  __shared__ float w[8192];
  const int Bf[9]={1,8,32,32,32,32,32,8,1};
  if(tid==0) v[0]=1.0;
  __syncthreads();
  for(int y=0;y<8;y++){
    int a=Bf[y], b=Bf[y+1];
    const double* By=bot+y*8192;
    const double* Ty=top+y*8192;
    for(int e=tid;e<a*b*8;e+=256){
      int k2=e&7; int bb=(e>>3)%b; int cc=e/(8*b);
      double acc=0.0;
      for(int aa=0;aa<a;aa++) acc+=v[aa*a+cc]*By[(aa*b+bb)*8+k2];
      w[(cc*b+bb)*8+k2]=(float)acc;
    }
    __syncthreads();
    for(int e=tid;e<b*b;e+=256){
      int dd=e%b; int bb=e/b;
      double acc=0.0;
      for(int cc=0;cc<a;cc++)
        for(int k2=0;k2<8;k2++)
          acc+=(double)w[(cc*b+bb)*8+k2]*Ty[(cc*b+dd)*8+k2];
      v2[bb*b+dd]=acc;
    }
    __syncthreads();
    for(int e=tid;e<b*b;e+=256) v[e]=v2[e];
    __syncthreads();
  }
  if(tid==0) out[s0+z]=(float)v[0];
}

// ---------------------------------------------------------------------------
static void run_compress_dual(double* ws, const float* peps, const int* x,
                              int s0, int ns, int xib, int xit, bool first,
                              hipStream_t stream){
  int njobs=2*ns;
  int Bin[9]; Bin[0]=1; Bin[8]=1;
  for(int i=1;i<8;i++) Bin[i]= first?8:((i==1||i==7)?8:32);
  int lraw[8], rraw[8];
  for(int y=0;y<8;y++){ lraw[y]=Bin[y]*((y>0)?8:1); rraw[y]=Bin[y+1]*((y<7)?8:1); }
  int kch[8];
  { int kp=1;
    for(int y=0;y<8;y++){ int n=(y<7)?Bin[y+1]*8:1; kch[y]=imin_(kp*8,n); kp=kch[y]; } }
  int keep[8];
  keep[7]=imin_(32, imin_(kch[6], 8));
  for(int y=6;y>=1;y--) keep[y]=imin_(32, imin_(kch[y-1], keep[y+1]*8));

  // forward: G^(1..7)
  for(int y=0;y<7;y++){
    k_absorb<<<dim3(Bin[y+1],1,njobs),256,0,stream>>>(ws,peps,x,s0,xib,xit,y,Bin[y],Bin[y+1]);
    int l=lraw[y], r8=rraw[y]*8;
    k_mmGT<<<dim3((l+15)/16,(r8+15)/16,njobs),dim3(16,16),0,stream>>>(
        ws,O_GSB+goff[y],O_TF,O_H2F,l,l,r8);
    k_gacc2<<<dim3(rraw[y]/16,rraw[y]/16,njobs),dim3(16,16),0,stream>>>(
        ws,O_H2F,O_TF,O_GSB+goff[y+1],l,rraw[y]);
    k_gscale<<<dim3(1,1,njobs),256,0,stream>>>(ws,O_GSB+goff[y+1],rraw[y]);
  }
  // backward
  for(int y=7;y>=1;y--){
    k_absorb<<<dim3(Bin[y+1],1,njobs),256,0,stream>>>(ws,peps,x,s0,xib,xit,y,Bin[y],Bin[y+1]);
    int ru=(y==7)?8:keep[y+1]*8;
    if(y==7) k_t2mp<<<dim3(2,1,njobs),256,0,stream>>>(ws,lraw[7]*8);
    else     k_mp<<<dim3(lraw[y],1,njobs),256,0,stream>>>(ws,O_TF,O_C,O_MP,rraw[y],keep[y+1]);
    int l=lraw[y];
    k_mm<<<dim3((l+15)/16,(ru+15)/16,njobs),dim3(16,16),0,stream>>>(
        ws,O_GSB+goff[y],O_MP,O_H,l,l,ru);
    k_mm_tn<<<dim3((ru+15)/16,(ru+15)/16,njobs),dim3(16,16),0,stream>>>(
        ws,O_MP,O_H,O_S,ru,l,ru);
    if(ru<=64)
      k_eig_direct<<<dim3(1,1,njobs),256,0,stream>>>(ws,O_S,O_MP,l,ru,keep[y],
                    O_NEW+y*8192,O_C);
    else
      k_eig_sub<<<dim3(1,1,njobs),256,0,stream>>>(ws,O_S,O_MP,l,keep[y],
                    O_NEW+y*8192,O_C);
  }
  // site 0: ts0 = T_0 * C_1
  k_absorb<<<dim3(Bin[1],1,njobs),256,0,stream>>>(ws,peps,x,s0,xib,xit,0,1,Bin[1]);
  k_mp<<<dim3(1,1,njobs),256,0,stream>>>(ws,O_TF,O_C,O_NEW+0,rraw[0],keep[1]);
  k_copy<<<dim3(32,1,njobs),256,0,stream>>>(ws);
}

extern "C" void kernel_launch(void* const* d_in, const int* in_sizes, int n_in,
                              void* d_out, int out_size, void* d_ws, size_t ws_size,
                              hipStream_t stream){
  const int*   x    = (const int*)d_in[0];     // (16,64) int32
  const float* peps = (const float*)d_in[1];   // (8,8,8,8,8,8,2) f32
  float* out = (float*)d_out;                  // 16 f32
  double* ws = (double*)d_ws;
  size_t samp_bytes = (size_t)2*SAMP_J*sizeof(double);   // 2 jobs/sample
  int max_chunk=(int)(ws_size/samp_bytes);
  if(max_chunk<1) max_chunk=1;
  if(max_chunk>16) max_chunk=16;
  for(int s0=0;s0<16;s0+=max_chunk){
    int ns=imin_(max_chunk,16-s0);
    int njobs=2*ns;
    k_init_row<<<dim3(8,1,njobs),64,0,stream>>>(ws,peps,x,s0);
    run_compress_dual(ws,peps,x,s0,ns,1,6,true ,stream);
    run_compress_dual(ws,peps,x,s0,ns,2,5,false,stream);
    run_compress_dual(ws,peps,x,s0,ns,3,4,false,stream);
    k_final<<<dim3(1,1,ns),256,0,stream>>>(ws,out,s0);
  }
}

// Round 4
// 327433.618 us; speedup vs baseline: 4.0717x; 2.4757x over previous
//
#include <hip/hip_runtime.h>

// ---------------------------------------------------------------------------
// fPEPS amplitude via boundary-MPS, chi=32. Metric ("left-Gram") formulation,
// f64 core with f32 bulk-tensor storage. Truncation = top eigvecs of M'^T G M'
// via in-LDS SHIFTED CholeskyQR subspace iteration (overflow-free, f64).
// Bottom & top chains fused per launch (blockIdx.z = sample*2+side).
// Lx=Ly=8, D=8, P=2, CHI=32.
// peps strides (f32): xi:65536 yi:8192 u:1024 d:128 l:16 r:2 s:1
//
// R1: cholqr solve -> in-LDS Rinv + staged GEMM; 1 barrier/col elim;
//     single-pass smul (64 acc).
// R2: QR1-per-step schedule (43->29 cholqr); closed-form tournament Jacobi
//     (3 barriers/round, no arrp); Ritz sweeps 6; LDS Omega sign table;
//     scratch overlaid into H2F region + right-sized G7 slot
//     (SAMP_J 1238016 -> 991296 doubles = 7.93MB/job).
// R3: identical resubmit (R2 bench infra-failed; measurement pending).
// ---------------------------------------------------------------------------

__host__ __device__ static inline int imin_(int a,int b){return a<b?a:b;}

// per-JOB workspace (doubles). job = sample*2 + side (0=bottom,1=top)
static constexpr int SAMP_J = 991296;    // 7.93 MB/job
static constexpr int O_CUR = 0;          // MPS, 8 sites x 8192 f64 [l][r][u]
static constexpr int O_NEW = 65536;
static constexpr int O_TF  = 131072;     // f32 T (524288 floats)
// forward-only H2 (f32, up to 524288 floats) shares [393216,655360) with the
// backward-only scratch below (temporally disjoint):
static constexpr int O_H2F = 393216;
static constexpr int O_MP  = 393216;     // M' (l x ru) f64      (65536)
static constexpr int O_H   = 458752;     // H = G*M'             (65536)
static constexpr int O_S   = 524288;     // S_hat (ru x ru)      (65536)
static constexpr int O_Y   = 589824;     // subspace Y (256x64)  (16384)
static constexpr int O_Y2  = 606208;     //                      (16384)
static constexpr int O_C   = 622592;     // C (l x keep)         (8192)
static constexpr int O_V   = 630784;     // V (ru x keep)        (8192)
static constexpr int O_GSB = 655360;     // G slots (f64), +goff[y]
// G slot sizes: y1:4096, y2..6:65536, y7:4096 -> end 655360+335873=991233

static const int goff[8] = {0,1,4097,69633,135169,200705,266241,331777};

// ---------------------------------------------------------------------------
__global__ void k_init_row(double* ws, const float* peps, const int* x, int s0){
  int z=blockIdx.z, y=blockIdx.x;
  int side=z&1, samp=z>>1;
  int xi = side?7:0;
  double* base = ws + (size_t)z*SAMP_J;
  double* cur = base + O_CUR + y*8192;
  int spin = x[(s0+samp)*64 + xi*8 + y];
  const float* pb = peps + (size_t)xi*65536 + (size_t)y*8192 + spin;
  int rd=(y<7)?8:1, ld=(y>0)?8:1;
  int ntot = ld*rd*8;
  for(int e=threadIdx.x; e<ntot; e+=blockDim.x){
    int u=e&7; int r=(e>>3)%rd; int l=e/(8*rd);
    float v = side ? pb[u*128 + l*16 + r*2] : pb[u*1024 + l*16 + r*2];
    cur[e]=(double)v;
  }
  if(y==0 && threadIdx.x==0) base[O_GSB]=1.0;   // G^(0)=[1]
}

// ---------------------------------------------------------------------------
// T[(x*Lp+lp)][(yb*Rp+rp)][u] = sum_p B[x][yb][p]*A[u,p,lp,rp]  (T stored f32)
__global__ __launch_bounds__(256)
void k_absorb(double* ws, const float* peps, const int* x, int s0,
              int xi_b, int xi_t, int y, int bl, int brdim){
  int z=blockIdx.z, yb=blockIdx.x;
  int side=z&1, samp=z>>1;
  int xi = side? xi_t : xi_b;
  int so = side? 128:1024, sc = side? 1024:128;
  double* base=ws+(size_t)z*SAMP_J;
  const double* B=base+O_CUR+y*8192;
  float* T=(float*)(base+O_TF);
  int spin=x[(s0+samp)*64+xi*8+y];
  const float* A=peps+(size_t)xi*65536+(size_t)y*8192+spin;
  int Lp=(y>0)?8:1, Rp=(y<7)?8:1;
  int rraw=brdim*Rp;
  __shared__ float As[4096];   // [u][p][lp][rp]
  __shared__ double Bs[256];   // [x][p]
  int nA=64*Lp*Rp;
  for(int e=threadIdx.x;e<nA;e+=256){
    int rp=e%Rp; int t=e/Rp; int lp=t%Lp; t/=Lp; int p=t&7; int u=t>>3;
    As[e]=A[u*so+p*sc+lp*16+rp*2];
  }
  for(int e=threadIdx.x;e<bl*8;e+=256)
    Bs[e]=B[((e>>3)*brdim+yb)*8+(e&7)];
  __syncthreads();
  int ntot=bl*Lp*Rp*8;
  for(int e=threadIdx.x;e<ntot;e+=256){
    int u=e&7; int t=e>>3; int rp=t%Rp; t/=Rp; int lp=t%Lp; int xx=t/Lp;
    double acc=0.0;
    #pragma unroll
    for(int p=0;p<8;p++) acc+=Bs[xx*8+p]*(double)As[((u*8+p)*Lp+lp)*Rp+rp];
    T[(size_t)((xx*Lp+lp)*rraw + yb*Rp+rp)*8 + u]=(float)acc;
  }
}

// ---------------------------------------------------------------------------
// H2(f32) = G(f64) * T(f32):  (ni x nk)(nk x nj)
__global__ void k_mmGT(double* ws, int Aoff, int Boff, int Coff, int ni, int nk, int nj){
  double* base=ws+(size_t)blockIdx.z*SAMP_J;
  const double* A=base+Aoff;
  const float* B=(const float*)(base+Boff);
  float* C=(float*)(base+Coff);
  __shared__ double As[16][17]; __shared__ float Bs[16][17];
  int tx=threadIdx.x, ty=threadIdx.y;
  int i0=blockIdx.x*16, j0=blockIdx.y*16;
  double acc=0.0;
  for(int k0=0;k0<nk;k0+=16){
    As[ty][tx]=(i0+ty<ni && k0+tx<nk)? A[(size_t)(i0+ty)*nk + k0+tx] : 0.0;
    Bs[ty][tx]=(k0+ty<nk && j0+tx<nj)? B[(size_t)(k0+ty)*nj + j0+tx] : 0.f;
    __syncthreads();
    #pragma unroll
    for(int t=0;t<16;t++) acc+=As[ty][t]*(double)Bs[t][tx];
    __syncthreads();
  }
  if(i0+ty<ni && j0+tx<nj) C[(size_t)(i0+ty)*nj + j0+tx]=(float)acc;
}

// f64 C = A*B and C = A^T*B (small, <=256^3)
__global__ void k_mm(double* ws, int Aoff, int Boff, int Coff, int ni, int nk, int nj){
  double* base=ws+(size_t)blockIdx.z*SAMP_J;
  const double* A=base+Aoff; const double* B=base+Boff; double* C=base+Coff;
  __shared__ double As[16][17], Bs[16][17];
  int tx=threadIdx.x, ty=threadIdx.y;
  int i0=blockIdx.x*16, j0=blockIdx.y*16;
  double acc=0.0;
  for(int k0=0;k0<nk;k0+=16){
    As[ty][tx]=(i0+ty<ni && k0+tx<nk)? A[(size_t)(i0+ty)*nk + k0+tx] : 0.0;
    Bs[ty][tx]=(k0+ty<nk && j0+tx<nj)? B[(size_t)(k0+ty)*nj + j0+tx] : 0.0;
    __syncthreads();
    #pragma unroll
    for(int t=0;t<16;t++) acc+=As[ty][t]*Bs[t][tx];
    __syncthreads();
  }
  if(i0+ty<ni && j0+tx<nj) C[(size_t)(i0+ty)*nj + j0+tx]=acc;
}
__global__ void k_mm_tn(double* ws, int Aoff, int Boff, int Coff, int ni, int nk, int nj){
  double* base=ws+(size_t)blockIdx.z*SAMP_J;
  const double* A=base+Aoff; const double* B=base+Boff; double* C=base+Coff;
  __shared__ double As[16][17], Bs[16][17];
  int tx=threadIdx.x, ty=threadIdx.y;
  int i0=blockIdx.x*16, j0=blockIdx.y*16;
  double acc=0.0;
  for(int k0=0;k0<nk;k0+=16){
    As[ty][tx]=(k0+ty<nk && i0+tx<ni)? A[(size_t)(k0+ty)*ni + i0+tx] : 0.0;
    Bs[ty][tx]=(k0+ty<nk && j0+tx<nj)? B[(size_t)(k0+ty)*nj + j0+tx] : 0.0;
    __syncthreads();
    #pragma unroll
    for(int t=0;t<16;t++) acc+=As[t][ty]*Bs[t][tx];
    __syncthreads();
  }
  if(i0+ty<ni && j0+tx<nj) C[(size_t)(i0+ty)*nj + j0+tx]=acc;
}

// ---------------------------------------------------------------------------
// G'(f64)[r][r'] = sum_{l,u} H2f[(l r u)] * Tf[(l r' u)]; upper + mirror
__global__ void k_gacc2(double* ws, int H2off, int Toff, int Goff, int ldim, int rdim){
  int bx=blockIdx.x, by=blockIdx.y;
  if(by<bx) return;
  double* base=ws+(size_t)blockIdx.z*SAMP_J;
  const float* H2=(const float*)(base+H2off);
  const float* T=(const float*)(base+Toff);
  double* G=base+Goff;
  __shared__ float As[16][17], Bs[16][17];
  int tx=threadIdx.x, ty=threadIdx.y;
  int r0=bx*16, r1=by*16;
  double acc=0.0;
  int ktot=ldim*8;
  for(int k0=0;k0<ktot;k0+=16){
    int kk=k0+ty; int l2=kk>>3; int u=kk&7;
    As[ty][tx]=(kk<ktot)? H2[((size_t)l2*rdim + r0+tx)*8 + u] : 0.f;
    Bs[ty][tx]=(kk<ktot)? T [((size_t)l2*rdim + r1+tx)*8 + u] : 0.f;
    __syncthreads();
    #pragma unroll
    for(int t=0;t<16;t++) acc+=(double)As[t][ty]*(double)Bs[t][tx];
    __syncthreads();
  }
  G[(size_t)(r0+ty)*rdim + r1+tx]=acc;
  if(by>bx) G[(size_t)(r1+tx)*rdim + r0+ty]=acc;
}

__global__ void k_gscale(double* ws, int Goff, int n){
  int tid=threadIdx.x;
  double* base=ws+(size_t)blockIdx.z*SAMP_J;
  double* G=base+Goff;
  __shared__ double red[256]; __shared__ double s_sc;
  double mx=0.0;
  for(int i=tid;i<n;i+=256) mx=fmax(mx,fabs(G[(size_t)i*n+i]));
  red[tid]=mx; __syncthreads();
  for(int w=128;w>0;w>>=1){ if(tid<w) red[tid]=fmax(red[tid],red[tid+w]); __syncthreads(); }
  if(tid==0) s_sc=(red[0]>0.0)?1.0/red[0]:1.0;
  __syncthreads();
  double sc=s_sc;
  for(int e=tid;e<n*n;e+=256) G[e]*=sc;
}

// ---------------------------------------------------------------------------
// M(f64)[li][(k*8+u)] = sum_r Tf[(li*rraw+r)*8+u] * C[r*keep+k]
__global__ __launch_bounds__(256)
void k_mp(double* ws, int Toff, int Coff, int Moff, int rraw, int keep){
  int li=blockIdx.x, tid=threadIdx.x;
  double* base=ws+(size_t)blockIdx.z*SAMP_J;
  const float* T=(const float*)(base+Toff) + (size_t)li*rraw*8;
  const double* Cc=base+Coff;
  double* M=base+Moff+(size_t)li*keep*8;
  __shared__ float Ts[2048];
  for(int e=tid;e<rraw*8;e+=256) Ts[e]=T[e];
  __syncthreads();
  for(int e=tid;e<keep*8;e+=256){
    int u=e&7, k=e>>3;
    double acc=0.0;
    for(int r=0;r<rraw;r++) acc+=(double)Ts[r*8+u]*Cc[(size_t)r*keep+k];
    M[k*8+u]=acc;
  }
}

__global__ void k_t2mp(double* ws, int n){
  double* base=ws+(size_t)blockIdx.z*SAMP_J;
  const float* T=(const float*)(base+O_TF);
  for(int e=blockIdx.x*blockDim.x+threadIdx.x;e<n;e+=gridDim.x*blockDim.x)
    base[O_MP+e]=(double)T[e];
}

// ---------------------------------------------------------------------------
// Cyclic Jacobi, closed-form round-robin (circle method): round r pairs
// {a,b} with a+b == r (mod q-1), plus (q-1, r*inv2 mod (q-1)).
// 3 barriers/round. q must be even.
__device__ void dev_jacobi(double* K, float* W, int q, int tid, int sweeps,
                           double* csC, double* csS, int* csP, int* csQ){
  int m=q-1, npairs=q>>1;
  int L=256/npairs;                // lanes per pair
  int inv2=(m+1)>>1;               // 2^{-1} mod m (m odd)
  for(int sweep=0;sweep<sweeps;sweep++)
  for(int rnd=0;rnd<m;rnd++){
    if(tid<npairs){
      int i0=(int)(((long long)rnd*(long long)inv2)%m);
      int p,qq;
      if(tid==0){ p=i0; qq=q-1; }
      else {
        p=i0+tid; if(p>=m) p-=m;
        qq=i0-tid; if(qq<0) qq+=m;
      }
      if(p>qq){int t=p;p=qq;qq=t;}
      double c=1.0,s2=0.0;
      double apq=K[p*64+qq];
      double app=K[p*64+p], aqq=K[qq*64+qq];
      if(fabs(apq) > 1e-18*(fabs(app)+fabs(aqq))+1e-300){
        double tau=(aqq-app)/(2.0*apq);
        double t=(tau>=0.0?1.0:-1.0)/(fabs(tau)+sqrt(1.0+tau*tau));
        c=1.0/sqrt(1.0+t*t); s2=t*c;
      }
      csP[tid]=p; csQ[tid]=qq; csC[tid]=c; csS[tid]=s2;
    }
    __syncthreads();
    int pr=tid/L, lane=tid%L;
    {
      int p=csP[pr], qq=csQ[pr];
      double c=csC[pr], s2=csS[pr];
      for(int j=lane;j<q;j+=L){
        double kp=K[p*64+j], kq=K[qq*64+j];
        K[p*64+j]=c*kp-s2*kq; K[qq*64+j]=s2*kp+c*kq;
      }
    }
    __syncthreads();
    {
      int p=csP[pr], qq=csQ[pr];
      double c=csC[pr], s2=csS[pr];
      float cf=(float)c, sf=(float)s2;
      for(int j=lane;j<q;j+=L){
        double kp=K[j*64+p], kq=K[j*64+qq];
        K[j*64+p]=c*kp-s2*kq; K[j*64+qq]=s2*kp+c*kq;
        float wp=W[j*64+p], wq=W[j*64+qq];
        W[j*64+p]=cf*wp-sf*wq; W[j*64+qq]=sf*wp+cf*wq;
      }
    }
    __syncthreads();
  }
}

__device__ void dev_select(const double* K, int q, int keep, int tid,
                           double* evals, int* idxs){
  if(tid==0){
    for(int a=0;a<q;a++){ evals[a]=K[a*64+a]; idxs[a]=a; }
    int lim=imin_(keep,q);
    for(int j=0;j<lim;j++){
      int bm=j;
      for(int a=j+1;a<q;a++) if(evals[idxs[a]]>evals[idxs[bm]]) bm=a;
      int t=idxs[j]; idxs[j]=idxs[bm]; idxs[bm]=t;
    }
  }
  __syncthreads();
}

// f64 CGS2 of V columns (n rows, keep cols, row-major stride keep)
__device__ void dev_orthV(double* V, int n, int keep, double* red){
  int tid=threadIdx.x;
  for(int j=0;j<keep;j++){
    double vj=(tid<n)? V[(size_t)tid*keep+j] : 0.0;
    for(int pass=0;pass<2;pass++){
      for(int t=0;t<j;t++){
        double vt=(tid<n)? V[(size_t)tid*keep+t] : 0.0;
        double p=vj*vt;
        for(int off=1;off<64;off<<=1) p+=__shfl_xor(p,off);
        if((tid&63)==0) red[tid>>6]=p;
        __syncthreads();
        double d=red[0]+red[1]+red[2]+red[3];
        vj-=d*vt;
        __syncthreads();
      }
    }
    double p=vj*vj;
    for(int off=1;off<64;off<<=1) p+=__shfl_xor(p,off);
    if((tid&63)==0) red[tid>>6]=p;
    __syncthreads();
    double nrm=red[0]+red[1]+red[2]+red[3];
    vj=vj/sqrt(fmax(nrm,1e-300));
    if(tid<n) V[(size_t)tid*keep+j]=vj;
    __syncthreads();
  }
}

// ---------------------------------------------------------------------------
// direct path (ru<=64): Jacobi on S; f64 orthonormalized V; ts=V^T, C=M'*V
__global__ __launch_bounds__(256)
void k_eig_direct(double* ws, int Soff, int MPoff, int l, int ru, int keep,
                  int newoff, int Coff){
  int tid=threadIdx.x;
  double* base=ws+(size_t)blockIdx.z*SAMP_J;
  const double* S=base+Soff;
  const double* MP=base+MPoff;
  double* C=base+Coff;
  double* NM=base+newoff;
  double* V=base+O_V;
  __shared__ double K[64*64];
  __shared__ float W[64*64];
  __shared__ double csC[32], csS[32];
  __shared__ int csP[32], csQ[32];
  __shared__ double evals[64]; __shared__ int idxs[64];
  __shared__ double red[4];
  int q=ru;
  for(int e=tid;e<q*q;e+=256){
    int a=e/q,b=e%q;
    K[a*64+b]=0.5*(S[(size_t)a*q+b]+S[(size_t)b*q+a]);
    W[a*64+b]=(a==b)?1.f:0.f;
  }
  __syncthreads();
  dev_jacobi(K,W,q,tid,8,csC,csS,csP,csQ);
  dev_select(K,q,keep,tid,evals,idxs);
  for(int e=tid;e<ru*keep;e+=256){
    int col=e/keep, j=e%keep;
    V[e]=(double)W[col*64+idxs[j]];
  }
  __syncthreads();
  dev_orthV(V,ru,keep,red);
  for(int e=tid;e<keep*ru;e+=256){
    int j=e/ru, col=e%ru;
    NM[e]=V[(size_t)col*keep+j];
  }
  for(int e=tid;e<l*keep;e+=256){
    int i=e/keep, j=e%keep;
    const double* Mi=MP+(size_t)i*ru;
    double acc=0.0;
    for(int c=0;c<ru;c++) acc+=Mi[c]*V[(size_t)c*keep+j];
    C[e]=acc;
  }
}

// ---------------------------------------------------------------------------
// Yout = sinv * S * Yin  (S 256x256 f64 global; Y 256x64 f64 global)
// single pass, 64 f64 accumulators (needs launch_bounds(256,1): no spill)
__device__ void dev_smul(const double* S, const double* Yin, double* Yout,
                         double* Yt, double sinv, int tid){
  double acc[64];
  #pragma unroll
  for(int j=0;j<64;j++) acc[j]=0.0;
  for(int cb=0;cb<16;cb++){
    __syncthreads();
    for(int e=tid;e<1024;e+=256) Yt[e]=Yin[cb*1024+e];
    __syncthreads();
    const double* Srow=S+(size_t)tid*256+cb*16;
    for(int c=0;c<16;c++){
      double sv=Srow[c];
      const double* Yr=Yt+c*64;
      #pragma unroll
      for(int j=0;j<64;j++) acc[j]+=sv*Yr[j];
    }
  }
  #pragma unroll
  for(int j=0;j<64;j++) Yout[(size_t)tid*64+j]=acc[j]*sinv;
  __syncthreads();
}

// ---------------------------------------------------------------------------
// SHIFTED CholeskyQR pass on Yg (256 x ncols, row-major, f64 global).
// Gram+lam*I = R^T R (R upper in Kd, stride 64). Then Ri = R^{-1} built in
// LDS (one column per lane, back-substitution), and X = Y * Ri applied as a
// staged GEMM: coalesced global traffic, LDS-resident inner loops.
// Pivots >= lam/4 > 0: overflow-free in f64. Junk (rank-deficient) columns
// come out as bounded small-norm vectors.
__device__ void dev_cholqr(double* Yg, int ncols, double* Kd, double* Yt,
                           double* Ri, double* shv, int tid){
  int rpb=1024/ncols, nblk=256/rpb, n2=ncols*ncols;
  for(int e=tid;e<n2;e+=256) Kd[(e/ncols)*64+(e%ncols)]=0.0;
  for(int b=0;b<nblk;b++){
    __syncthreads();
    for(int e=tid;e<1024;e+=256) Yt[e]=Yg[b*1024+e];
    __syncthreads();
    for(int e=tid;e<n2;e+=256){
      int a=e/ncols, c=e%ncols;
      if(c>=a){
        double acc=0.0;
        for(int r=0;r<rpb;r++) acc+=Yt[r*ncols+a]*Yt[r*ncols+c];
        Kd[a*64+c]+=acc;
      }
    }
  }
  __syncthreads();
  if(tid==0){
    double tr=0.0;
    for(int j=0;j<ncols;j++) tr+=Kd[j*64+j];
    shv[0]=(tr/ncols)*1e-14+1e-290;
  }
  __syncthreads();
  double lam=shv[0];
  for(int i=tid;i<ncols;i+=256) Kd[i*64+i]+=lam;
  __syncthreads();
  // raw upper elimination; diag holds d_j >= lam/4. One barrier per column:
  // pivot clamp computed redundantly per-thread (idempotent).
  for(int j=0;j<ncols;j++){
    double d=Kd[j*64+j];
    if(!(d>lam*0.25)) d=lam*0.25;
    double invd=1.0/d;
    if(tid==0) Kd[j*64+j]=d;
    int w=ncols-1-j;
    for(int e=tid;e<w*w;e+=256){
      int i2=j+1+e/w, k2=j+1+e%w;
      if(k2>=i2) Kd[i2*64+k2]-=Kd[j*64+i2]*Kd[j*64+k2]*invd;
    }
    __syncthreads();
  }
  // row-normalize -> R (upper, R_jj = sqrt(d_j))
  for(int i=tid;i<ncols;i+=256) Yt[i]=1.0/sqrt(Kd[i*64+i]);
  __syncthreads();
  for(int e=tid;e<n2;e+=256){
    int i=e/ncols, k=e%ncols;
    if(k>=i) Kd[i*64+k]*=Yt[i];
  }
  __syncthreads();
  // Ri = R^{-1} (upper, stride 66). Column j by lane j: back-substitution.
  if(tid<ncols){
    int j=tid;
    Ri[j*66+j]=1.0/Kd[j*64+j];
    for(int i=j-1;i>=0;i--){
      double s=0.0;
      for(int k=i+1;k<=j;k++) s+=Kd[i*64+k]*Ri[k*66+j];
      Ri[i*66+j]=-s/Kd[i*64+i];
    }
  }
  __syncthreads();
  // X = Y * Ri, staged through Yt per row-block. thread: j = tid%ncols
  // (coalesced stores), rg = tid/ncols covering 4 rows of the block.
  {
    int j=tid%ncols, rg=tid/ncols;
    for(int b=0;b<nblk;b++){
      for(int e=tid;e<1024;e+=256) Yt[e]=Yg[b*1024+e];
      __syncthreads();
      double xr[4];
      #pragma unroll
      for(int r4=0;r4<4;r4++){
        int r=rg*4+r4;
        double acc=0.0;
        for(int k=0;k<=j;k++) acc+=Yt[r*ncols+k]*Ri[k*66+j];
        xr[r4]=acc;
      }
      __syncthreads();
      #pragma unroll
      for(int r4=0;r4<4;r4++){
        int r=rg*4+r4;
        Yg[(size_t)b*1024 + r*ncols + j]=xr[r4];
      }
    }
  }
  __syncthreads();
}

// subspace path (ru==256): 20-step power iteration, QR1/step (+QR2 every 4th
// and before Ritz), Ritz via Jacobi, f64 V re-orth
__global__ __launch_bounds__(256,1)
void k_eig_sub(double* ws, int Soff, int MPoff, int l, int keep,
               int newoff, int Coff){
  const int RU=256;
  int tid=threadIdx.x;
  double* base=ws+(size_t)blockIdx.z*SAMP_J;
  const double* S=base+Soff;
  const double* MP=base+MPoff;
  double* Ya=base+O_Y;
  double* Yb=base+O_Y2;
  double* V =base+O_V;
  double* C =base+Coff;
  double* NM=base+newoff;
  __shared__ double Kd[64*64];     // 32 KB
  __shared__ double Ri[64*66];     // 33 KB (R^{-1} for cholqr)
  __shared__ float  Wf[64*64];     // 16 KB (Jacobi eigvecs only)
  __shared__ double Yt[1024];      // 8 KB
  __shared__ double red[260];
  __shared__ unsigned long long om[256];  // Omega sign bitmasks
  __shared__ double csC[32], csS[32];
  __shared__ int csP[32], csQ[32];
  __shared__ double evals[64]; __shared__ int idxs[64];

  // sinv = 1/max diag(S) (scale-invariant normalization)
  double mx=0.0;
  for(int i=tid;i<RU;i+=256) mx=fmax(mx,S[(size_t)i*RU+i]);
  red[tid]=mx; __syncthreads();
  for(int w=128;w>0;w>>=1){ if(tid<w) red[tid]=fmax(red[tid],red[tid+w]); __syncthreads(); }
  double sinv=(red[0]>0.0)?1.0/red[0]:1.0;
  __syncthreads();

  // Omega sign table (bitwise-identical to per-term hash)
  for(int c2=tid;c2<256;c2+=256){
    unsigned long long mask=0ull;
    for(int j=0;j<64;j++){
      unsigned h=(unsigned)(c2*1103515245u)^(unsigned)((j+1)*2654435761u);
      h^=h>>13; h*=0x9E3779B1u;
      mask |= ((unsigned long long)((h>>16)&1u))<<j;
    }
    om[c2]=mask;
  }
  __syncthreads();

  // Ya = sinv * S * Omega (deterministic +-1)
  for(int e=tid;e<RU*64;e+=256){
    int i=e>>6, j=e&63;
    const double* Si=S+(size_t)i*RU;
    double acc=0.0;
    for(int c2=0;c2<RU;c2++)
      acc += ((om[c2]>>j)&1ull)? Si[c2] : -Si[c2];
    Ya[e]=acc*sinv;
  }
  __syncthreads();
  dev_cholqr(Ya,64,Kd,Yt,Ri,red+256,tid);
  dev_cholqr(Ya,64,Kd,Yt,Ri,red+256,tid);
  for(int it=0;it<20;it++){
    dev_smul(S,Ya,Yb,Yt,sinv,tid);
    dev_cholqr(Yb,64,Kd,Yt,Ri,red+256,tid);
    if((it&3)==3) dev_cholqr(Yb,64,Kd,Yt,Ri,red+256,tid);
    double* t=Ya; Ya=Yb; Yb=t;
  }
  dev_cholqr(Ya,64,Kd,Yt,Ri,red+256,tid);   // ensure orthonormal pre-Ritz
  dev_smul(S,Ya,Yb,Yt,sinv,tid);            // Yb = S*Ya (unorthogonalized)

  // Ritz: K = Ya^T Yb
  for(int e=tid;e<4096;e+=256) Kd[e]=0.0;
  for(int b=0;b<32;b++){
    __syncthreads();
    for(int e=tid;e<512;e+=256){ Yt[e]=Ya[b*512+e]; Yt[512+e]=Yb[b*512+e]; }
    __syncthreads();
    for(int i=0;i<16;i++){
      int e2=tid*16+i; int a=e2>>6, c=e2&63;
      double acc=Kd[e2];
      for(int r=0;r<8;r++) acc+=Yt[r*64+a]*Yt[512+r*64+c];
      Kd[e2]=acc;
    }
  }
  __syncthreads();
  for(int e=tid;e<4096;e+=256){
    int a=e>>6,c=e&63;
    if(a<c){ double m=0.5*(Kd[a*64+c]+Kd[c*64+a]); Kd[a*64+c]=m; Kd[c*64+a]=m; }
  }
  __syncthreads();
  for(int e=tid;e<4096;e+=256) Wf[e]=((e>>6)==(e&63))?1.f:0.f;
  __syncthreads();
  dev_jacobi(Kd,Wf,64,tid,6,csC,csS,csP,csQ);
  dev_select(Kd,64,keep,tid,evals,idxs);
  // V = Ya * W[:,sel]
  for(int e=tid;e<RU*keep;e+=256){
    int i=e/keep, j=e%keep; int vj=idxs[j];
    const double* Yr=Ya+(size_t)i*64;
    double acc=0.0;
    for(int t=0;t<64;t++) acc+=Yr[t]*(double)Wf[t*64+vj];
    V[e]=acc;
  }
  __syncthreads();
  dev_cholqr(V,keep,Kd,Yt,Ri,red+256,tid);   // f64 exact-projector fix
  for(int e=tid;e<keep*RU;e+=256){
    int j=e/RU, col=e%RU;
    NM[e]=V[(size_t)col*keep+j];
  }
  for(int e=tid;e<l*keep;e+=256){
    int i=e/keep, j=e%keep;
    const double* Mi=MP+(size_t)i*RU;
    double acc=0.0;
    for(int col=0;col<RU;col++) acc+=Mi[col]*V[(size_t)col*keep+j];
    C[e]=acc;
  }
}

// ---------------------------------------------------------------------------
__global__ void k_copy(double* ws){
  double* base=ws+(size_t)blockIdx.z*SAMP_J;
  for(int e=blockIdx.x*blockDim.x+threadIdx.x;e<65536;e+=gridDim.x*blockDim.x)
    base[O_CUR+e]=base[O_NEW+e];
}

// final chain contraction: bottom=job(2s), top=job(2s+1)
__global__ __launch_bounds__(256)
void k_final(double* ws, float* out, int s0){
  int z=blockIdx.z, tid=threadIdx.x;
  const double* bot=ws+(size_t)(2*z)*SAMP_J+O_CUR;
  const double* top=ws+(size_t)(2*z+1)*SAMP_J+O_CUR;
  __shared__ double v[1024], v2[1024];
  __shared__ float w[8192];
  const int Bf[9]={1,8,32,32,32,32,32,8,1};
  if(tid==0) v[0]=1.0;
  __syncthreads();
  for(int y=0;y<8;y++){
    int a=Bf[y], b=Bf[y+1];
    const double* By=bot+y*8192;
    const double* Ty=top+y*8192;
    for(int e=tid;e<a*b*8;e+=256){
      int k2=e&7; int bb=(e>>3)%b; int cc=e/(8*b);
      double acc=0.0;
      for(int aa=0;aa<a;aa++) acc+=v[aa*a+cc]*By[(aa*b+bb)*8+k2];
      w[(cc*b+bb)*8+k2]=(float)acc;
    }
    __syncthreads();
    for(int e=tid;e<b*b;e+=256){
      int dd=e%b; int bb=e/b;
      double acc=0.0;
      for(int cc=0;cc<a;cc++)
        for(int k2=0;k2<8;k2++)
          acc+=(double)w[(cc*b+bb)*8+k2]*Ty[(cc*b+dd)*8+k2];
      v2[bb*b+dd]=acc;
    }
    __syncthreads();
    for(int e=tid;e<b*b;e+=256) v[e]=v2[e];
    __syncthreads();
  }
  if(tid==0) out[s0+z]=(float)v[0];
}

// ---------------------------------------------------------------------------
static void run_compress_dual(double* ws, const float* peps, const int* x,
                              int s0, int ns, int xib, int xit, bool first,
                              hipStream_t stream){
  int njobs=2*ns;
  int Bin[9]; Bin[0]=1; Bin[8]=1;
  for(int i=1;i<8;i++) Bin[i]= first?8:((i==1||i==7)?8:32);
  int lraw[8], rraw[8];
  for(int y=0;y<8;y++){ lraw[y]=Bin[y]*((y>0)?8:1); rraw[y]=Bin[y+1]*((y<7)?8:1); }
  int kch[8];
  { int kp=1;
    for(int y=0;y<8;y++){ int n=(y<7)?Bin[y+1]*8:1; kch[y]=imin_(kp*8,n); kp=kch[y]; } }
  int keep[8];
  keep[7]=imin_(32, imin_(kch[6], 8));
  for(int y=6;y>=1;y--) keep[y]=imin_(32, imin_(kch[y-1], keep[y+1]*8));

  // forward: G^(1..7)
  for(int y=0;y<7;y++){
    k_absorb<<<dim3(Bin[y+1],1,njobs),256,0,stream>>>(ws,peps,x,s0,xib,xit,y,Bin[y],Bin[y+1]);
    int l=lraw[y], r8=rraw[y]*8;
    k_mmGT<<<dim3((l+15)/16,(r8+15)/16,njobs),dim3(16,16),0,stream>>>(
        ws,O_GSB+goff[y],O_TF,O_H2F,l,l,r8);
    k_gacc2<<<dim3(rraw[y]/16,rraw[y]/16,njobs),dim3(16,16),0,stream>>>(
        ws,O_H2F,O_TF,O_GSB+goff[y+1],l,rraw[y]);
    k_gscale<<<dim3(1,1,njobs),256,0,stream>>>(ws,O_GSB+goff[y+1],rraw[y]);
  }
  // backward
  for(int y=7;y>=1;y--){
    k_absorb<<<dim3(Bin[y+1],1,njobs),256,0,stream>>>(ws,peps,x,s0,xib,xit,y,Bin[y],Bin[y+1]);
    int ru=(y==7)?8:keep[y+1]*8;
    if(y==7) k_t2mp<<<dim3(2,1,njobs),256,0,stream>>>(ws,lraw[7]*8);
    else     k_mp<<<dim3(lraw[y],1,njobs),256,0,stream>>>(ws,O_TF,O_C,O_MP,rraw[y],keep[y+1]);
    int l=lraw[y];
    k_mm<<<dim3((l+15)/16,(ru+15)/16,njobs),dim3(16,16),0,stream>>>(
        ws,O_GSB+goff[y],O_MP,O_H,l,l,ru);
    k_mm_tn<<<dim3((ru+15)/16,(ru+15)/16,njobs),dim3(16,16),0,stream>>>(
        ws,O_MP,O_H,O_S,ru,l,ru);
    if(ru<=64)
      k_eig_direct<<<dim3(1,1,njobs),256,0,stream>>>(ws,O_S,O_MP,l,ru,keep[y],
                    O_NEW+y*8192,O_C);
    else
      k_eig_sub<<<dim3(1,1,njobs),256,0,stream>>>(ws,O_S,O_MP,l,keep[y],
                    O_NEW+y*8192,O_C);
  }
  // site 0: ts0 = T_0 * C_1
  k_absorb<<<dim3(Bin[1],1,njobs),256,0,stream>>>(ws,peps,x,s0,xib,xit,0,1,Bin[1]);
  k_mp<<<dim3(1,1,njobs),256,0,stream>>>(ws,O_TF,O_C,O_NEW+0,rraw[0],keep[1]);
  k_copy<<<dim3(32,1,njobs),256,0,stream>>>(ws);
}

extern "C" void kernel_launch(void* const* d_in, const int* in_sizes, int n_in,
                              void* d_out, int out_size, void* d_ws, size_t ws_size,
                              hipStream_t stream){
  const int*   x    = (const int*)d_in[0];     // (16,64) int32
  const float* peps = (const float*)d_in[1];   // (8,8,8,8,8,8,2) f32
  float* out = (float*)d_out;                  // 16 f32
  double* ws = (double*)d_ws;
  size_t samp_bytes = (size_t)2*SAMP_J*sizeof(double);   // 2 jobs/sample
  int max_chunk=(int)(ws_size/samp_bytes);
  if(max_chunk<1) max_chunk=1;
  if(max_chunk>16) max_chunk=16;
  for(int s0=0;s0<16;s0+=max_chunk){
    int ns=imin_(max_chunk,16-s0);
    int njobs=2*ns;
    k_init_row<<<dim3(8,1,njobs),64,0,stream>>>(ws,peps,x,s0);
    run_compress_dual(ws,peps,x,s0,ns,1,6,true ,stream);
    run_compress_dual(ws,peps,x,s0,ns,2,5,false,stream);
    run_compress_dual(ws,peps,x,s0,ns,3,4,false,stream);
    k_final<<<dim3(1,1,ns),256,0,stream>>>(ws,out,s0);
  }
}

// Round 7
// 154549.915 us; speedup vs baseline: 8.6265x; 2.1186x over previous
//
#include <hip/hip_runtime.h>

// ---------------------------------------------------------------------------
// fPEPS amplitude via boundary-MPS, chi=32. Metric ("left-Gram") formulation,
// f64 core with f32 bulk-tensor storage. Truncation = top eigvecs of M'^T G M'
// via in-LDS SHIFTED CholeskyQR subspace iteration (overflow-free, f64).
// Bottom & top chains fused per launch (blockIdx.z = sample*2+side).
// Lx=Ly=8, D=8, P=2, CHI=32.
//
// R1: cholqr solve -> in-LDS Rinv + staged GEMM. R2: schedule+workspace slim
// (single chunk, 16 samples resident). R4: k_eig_sub latency attack —
// 512 threads (2 waves/SIMD), LDS stride 65 for 64x64 matrices (bank fix),
// degree-2 power schedule (cholqr 29->14), parallel top-k select.
// R5/R6: identical resubmits (bench infra-failed twice; measurement pending).
// ---------------------------------------------------------------------------

__host__ __device__ static inline int imin_(int a,int b){return a<b?a:b;}

static constexpr int SAMP_J = 991296;    // 7.93 MB/job
static constexpr int O_CUR = 0;
static constexpr int O_NEW = 65536;
static constexpr int O_TF  = 131072;
static constexpr int O_H2F = 393216;
static constexpr int O_MP  = 393216;
static constexpr int O_H   = 458752;
static constexpr int O_S   = 524288;
static constexpr int O_Y   = 589824;
static constexpr int O_Y2  = 606208;
static constexpr int O_C   = 622592;
static constexpr int O_V   = 630784;
static constexpr int O_GSB = 655360;

static const int goff[8] = {0,1,4097,69633,135169,200705,266241,331777};

// LDS row stride for 64x64 matrices (bank-conflict padding)
#define LDK 65

// ---------------------------------------------------------------------------
__global__ void k_init_row(double* ws, const float* peps, const int* x, int s0){
  int z=blockIdx.z, y=blockIdx.x;
  int side=z&1, samp=z>>1;
  int xi = side?7:0;
  double* base = ws + (size_t)z*SAMP_J;
  double* cur = base + O_CUR + y*8192;
  int spin = x[(s0+samp)*64 + xi*8 + y];
  const float* pb = peps + (size_t)xi*65536 + (size_t)y*8192 + spin;
  int rd=(y<7)?8:1, ld=(y>0)?8:1;
  int ntot = ld*rd*8;
  for(int e=threadIdx.x; e<ntot; e+=blockDim.x){
    int u=e&7; int r=(e>>3)%rd; int l=e/(8*rd);
    float v = side ? pb[u*128 + l*16 + r*2] : pb[u*1024 + l*16 + r*2];
    cur[e]=(double)v;
  }
  if(y==0 && threadIdx.x==0) base[O_GSB]=1.0;
}

// ---------------------------------------------------------------------------
__global__ __launch_bounds__(256)
void k_absorb(double* ws, const float* peps, const int* x, int s0,
              int xi_b, int xi_t, int y, int bl, int brdim){
  int z=blockIdx.z, yb=blockIdx.x;
  int side=z&1, samp=z>>1;
  int xi = side? xi_t : xi_b;
  int so = side? 128:1024, sc = side? 1024:128;
  double* base=ws+(size_t)z*SAMP_J;
  const double* B=base+O_CUR+y*8192;
  float* T=(float*)(base+O_TF);
  int spin=x[(s0+samp)*64+xi*8+y];
  const float* A=peps+(size_t)xi*65536+(size_t)y*8192+spin;
  int Lp=(y>0)?8:1, Rp=(y<7)?8:1;
  int rraw=brdim*Rp;
  __shared__ float As[4096];
  __shared__ double Bs[256];
  int nA=64*Lp*Rp;
  for(int e=threadIdx.x;e<nA;e+=256){
    int rp=e%Rp; int t=e/Rp; int lp=t%Lp; t/=Lp; int p=t&7; int u=t>>3;
    As[e]=A[u*so+p*sc+lp*16+rp*2];
  }
  for(int e=threadIdx.x;e<bl*8;e+=256)
    Bs[e]=B[((e>>3)*brdim+yb)*8+(e&7)];
  __syncthreads();
  int ntot=bl*Lp*Rp*8;
  for(int e=threadIdx.x;e<ntot;e+=256){
    int u=e&7; int t=e>>3; int rp=t%Rp; t/=Rp; int lp=t%Lp; int xx=t/Lp;
    double acc=0.0;
    #pragma unroll
    for(int p=0;p<8;p++) acc+=Bs[xx*8+p]*(double)As[((u*8+p)*Lp+lp)*Rp+rp];
    T[(size_t)((xx*Lp+lp)*rraw + yb*Rp+rp)*8 + u]=(float)acc;
  }
}

// ---------------------------------------------------------------------------
__global__ void k_mmGT(double* ws, int Aoff, int Boff, int Coff, int ni, int nk, int nj){
  double* base=ws+(size_t)blockIdx.z*SAMP_J;
  const double* A=base+Aoff;
  const float* B=(const float*)(base+Boff);
  float* C=(float*)(base+Coff);
  __shared__ double As[16][17]; __shared__ float Bs[16][17];
  int tx=threadIdx.x, ty=threadIdx.y;
  int i0=blockIdx.x*16, j0=blockIdx.y*16;
  double acc=0.0;
  for(int k0=0;k0<nk;k0+=16){
    As[ty][tx]=(i0+ty<ni && k0+tx<nk)? A[(size_t)(i0+ty)*nk + k0+tx] : 0.0;
    Bs[ty][tx]=(k0+ty<nk && j0+tx<nj)? B[(size_t)(k0+ty)*nj + j0+tx] : 0.f;
    __syncthreads();
    #pragma unroll
    for(int t=0;t<16;t++) acc+=As[ty][t]*(double)Bs[t][tx];
    __syncthreads();
  }
  if(i0+ty<ni && j0+tx<nj) C[(size_t)(i0+ty)*nj + j0+tx]=(float)acc;
}

__global__ void k_mm(double* ws, int Aoff, int Boff, int Coff, int ni, int nk, int nj){
  double* base=ws+(size_t)blockIdx.z*SAMP_J;
  const double* A=base+Aoff; const double* B=base+Boff; double* C=base+Coff;
  __shared__ double As[16][17], Bs[16][17];
  int tx=threadIdx.x, ty=threadIdx.y;
  int i0=blockIdx.x*16, j0=blockIdx.y*16;
  double acc=0.0;
  for(int k0=0;k0<nk;k0+=16){
    As[ty][tx]=(i0+ty<ni && k0+tx<nk)? A[(size_t)(i0+ty)*nk + k0+tx] : 0.0;
    Bs[ty][tx]=(k0+ty<nk && j0+tx<nj)? B[(size_t)(k0+ty)*nj + j0+tx] : 0.0;
    __syncthreads();
    #pragma unroll
    for(int t=0;t<16;t++) acc+=As[ty][t]*Bs[t][tx];
    __syncthreads();
  }
  if(i0+ty<ni && j0+tx<nj) C[(size_t)(i0+ty)*nj + j0+tx]=acc;
}
__global__ void k_mm_tn(double* ws, int Aoff, int Boff, int Coff, int ni, int nk, int nj){
  double* base=ws+(size_t)blockIdx.z*SAMP_J;
  const double* A=base+Aoff; const double* B=base+Boff; double* C=base+Coff;
  __shared__ double As[16][17], Bs[16][17];
  int tx=threadIdx.x, ty=threadIdx.y;
  int i0=blockIdx.x*16, j0=blockIdx.y*16;
  double acc=0.0;
  for(int k0=0;k0<nk;k0+=16){
    As[ty][tx]=(k0+ty<nk && i0+tx<ni)? A[(size_t)(k0+ty)*ni + i0+tx] : 0.0;
    Bs[ty][tx]=(k0+ty<nk && j0+tx<nj)? B[(size_t)(k0+ty)*nj + j0+tx] : 0.0;
    __syncthreads();
    #pragma unroll
    for(int t=0;t<16;t++) acc+=As[t][ty]*Bs[t][tx];
    __syncthreads();
  }
  if(i0+ty<ni && j0+tx<nj) C[(size_t)(i0+ty)*nj + j0+tx]=acc;
}

// ---------------------------------------------------------------------------
__global__ void k_gacc2(double* ws, int H2off, int Toff, int Goff, int ldim, int rdim){
  int bx=blockIdx.x, by=blockIdx.y;
  if(by<bx) return;
  double* base=ws+(size_t)blockIdx.z*SAMP_J;
  const float* H2=(const float*)(base+H2off);
  const float* T=(const float*)(base+Toff);
  double* G=base+Goff;
  __shared__ float As[16][17], Bs[16][17];
  int tx=threadIdx.x, ty=threadIdx.y;
  int r0=bx*16, r1=by*16;
  double acc=0.0;
  int ktot=ldim*8;
  for(int k0=0;k0<ktot;k0+=16){
    int kk=k0+ty; int l2=kk>>3; int u=kk&7;
    As[ty][tx]=(kk<ktot)? H2[((size_t)l2*rdim + r0+tx)*8 + u] : 0.f;
    Bs[ty][tx]=(kk<ktot)? T [((size_t)l2*rdim + r1+tx)*8 + u] : 0.f;
    __syncthreads();
    #pragma unroll
    for(int t=0;t<16;t++) acc+=(double)As[t][ty]*(double)Bs[t][tx];
    __syncthreads();
  }
  G[(size_t)(r0+ty)*rdim + r1+tx]=acc;
  if(by>bx) G[(size_t)(r1+tx)*rdim + r0+ty]=acc;
}

__global__ void k_gscale(double* ws, int Goff, int n){
  int tid=threadIdx.x;
  double* base=ws+(size_t)blockIdx.z*SAMP_J;
  double* G=base+Goff;
  __shared__ double red[256]; __shared__ double s_sc;
  double mx=0.0;
  for(int i=tid;i<n;i+=256) mx=fmax(mx,fabs(G[(size_t)i*n+i]));
  red[tid]=mx; __syncthreads();
  for(int w=128;w>0;w>>=1){ if(tid<w) red[tid]=fmax(red[tid],red[tid+w]); __syncthreads(); }
  if(tid==0) s_sc=(red[0]>0.0)?1.0/red[0]:1.0;
  __syncthreads();
  double sc=s_sc;
  for(int e=tid;e<n*n;e+=256) G[e]*=sc;
}

// ---------------------------------------------------------------------------
__global__ __launch_bounds__(256)
void k_mp(double* ws, int Toff, int Coff, int Moff, int rraw, int keep){
  int li=blockIdx.x, tid=threadIdx.x;
  double* base=ws+(size_t)blockIdx.z*SAMP_J;
  const float* T=(const float*)(base+Toff) + (size_t)li*rraw*8;
  const double* Cc=base+Coff;
  double* M=base+Moff+(size_t)li*keep*8;
  __shared__ float Ts[2048];
  for(int e=tid;e<rraw*8;e+=256) Ts[e]=T[e];
  __syncthreads();
  for(int e=tid;e<keep*8;e+=256){
    int u=e&7, k=e>>3;
    double acc=0.0;
    for(int r=0;r<rraw;r++) acc+=(double)Ts[r*8+u]*Cc[(size_t)r*keep+k];
    M[k*8+u]=acc;
  }
}

__global__ void k_t2mp(double* ws, int n){
  double* base=ws+(size_t)blockIdx.z*SAMP_J;
  const float* T=(const float*)(base+O_TF);
  for(int e=blockIdx.x*blockDim.x+threadIdx.x;e<n;e+=gridDim.x*blockDim.x)
    base[O_MP+e]=(double)T[e];
}

// ---------------------------------------------------------------------------
// Cyclic Jacobi, closed-form round-robin (circle method). Matrices at LDS
// stride LDK(=65). NT-agnostic (uses blockDim.x). 3 barriers/round.
__device__ void dev_jacobi(double* K, float* W, int q, int tid, int sweeps,
                           double* csC, double* csS, int* csP, int* csQ){
  int NT=blockDim.x;
  int m=q-1, npairs=q>>1;
  int L=NT/npairs;
  int inv2=(m+1)>>1;
  for(int sweep=0;sweep<sweeps;sweep++)
  for(int rnd=0;rnd<m;rnd++){
    if(tid<npairs){
      int i0=(int)(((long long)rnd*(long long)inv2)%m);
      int p,qq;
      if(tid==0){ p=i0; qq=q-1; }
      else {
        p=i0+tid; if(p>=m) p-=m;
        qq=i0-tid; if(qq<0) qq+=m;
      }
      if(p>qq){int t=p;p=qq;qq=t;}
      double c=1.0,s2=0.0;
      double apq=K[p*LDK+qq];
      double app=K[p*LDK+p], aqq=K[qq*LDK+qq];
      if(fabs(apq) > 1e-18*(fabs(app)+fabs(aqq))+1e-300){
        double tau=(aqq-app)/(2.0*apq);
        double t=(tau>=0.0?1.0:-1.0)/(fabs(tau)+sqrt(1.0+tau*tau));
        c=1.0/sqrt(1.0+t*t); s2=t*c;
      }
      csP[tid]=p; csQ[tid]=qq; csC[tid]=c; csS[tid]=s2;
    }
    __syncthreads();
    int pr=tid/L, lane=tid%L;
    {
      int p=csP[pr], qq=csQ[pr];
      double c=csC[pr], s2=csS[pr];
      for(int j=lane;j<q;j+=L){
        double kp=K[p*LDK+j], kq=K[qq*LDK+j];
        K[p*LDK+j]=c*kp-s2*kq; K[qq*LDK+j]=s2*kp+c*kq;
      }
    }
    __syncthreads();
    {
      int p=csP[pr], qq=csQ[pr];
      double c=csC[pr], s2=csS[pr];
      float cf=(float)c, sf=(float)s2;
      for(int j=lane;j<q;j+=L){
        double kp=K[j*LDK+p], kq=K[j*LDK+qq];
        K[j*LDK+p]=c*kp-s2*kq; K[j*LDK+qq]=s2*kp+c*kq;
        float wp=W[j*LDK+p], wq=W[j*LDK+qq];
        W[j*LDK+p]=cf*wp-sf*wq; W[j*LDK+qq]=sf*wp+cf*wq;
      }
    }
    __syncthreads();
  }
}

// parallel top-keep select: wave-0 argmax per pick (no serial LDS chain)
__device__ void dev_select(const double* K, int q, int keep, int tid,
                           double* evals, int* idxs){
  for(int a=tid;a<q;a+=blockDim.x) evals[a]=K[a*LDK+a];
  __syncthreads();
  if(tid<64){
    int a=tid;
    double v=(a<q)? evals[a] : -1.0e300;
    for(int j=0;j<keep;j++){
      double bv=v; int bi=a;
      for(int off=1;off<64;off<<=1){
        double ov=__shfl_xor(bv,off); int oi=__shfl_xor(bi,off);
        if(ov>bv || (ov==bv && oi<bi)){ bv=ov; bi=oi; }
      }
      if(a==bi) v=-1.0e300;
      if(tid==0) idxs[j]=bi;
    }
  }
  __syncthreads();
}

// f64 CGS2 of V columns (n rows, keep cols, row-major stride keep) [256 thr]
__device__ void dev_orthV(double* V, int n, int keep, double* red){
  int tid=threadIdx.x;
  for(int j=0;j<keep;j++){
    double vj=(tid<n)? V[(size_t)tid*keep+j] : 0.0;
    for(int pass=0;pass<2;pass++){
      for(int t=0;t<j;t++){
        double vt=(tid<n)? V[(size_t)tid*keep+t] : 0.0;
        double p=vj*vt;
        for(int off=1;off<64;off<<=1) p+=__shfl_xor(p,off);
        if((tid&63)==0) red[tid>>6]=p;
        __syncthreads();
        double d=red[0]+red[1]+red[2]+red[3];
        vj-=d*vt;
        __syncthreads();
      }
    }
    double p=vj*vj;
    for(int off=1;off<64;off<<=1) p+=__shfl_xor(p,off);
    if((tid&63)==0) red[tid>>6]=p;
    __syncthreads();
    double nrm=red[0]+red[1]+red[2]+red[3];
    vj=vj/sqrt(fmax(nrm,1e-300));
    if(tid<n) V[(size_t)tid*keep+j]=vj;
    __syncthreads();
  }
}

// ---------------------------------------------------------------------------
// direct path (ru<=64), 256 threads
__global__ __launch_bounds__(256)
void k_eig_direct(double* ws, int Soff, int MPoff, int l, int ru, int keep,
                  int newoff, int Coff){
  int tid=threadIdx.x;
  double* base=ws+(size_t)blockIdx.z*SAMP_J;
  const double* S=base+Soff;
  const double* MP=base+MPoff;
  double* C=base+Coff;
  double* NM=base+newoff;
  double* V=base+O_V;
  __shared__ double K[64*LDK];
  __shared__ float W[64*LDK];
  __shared__ double csC[32], csS[32];
  __shared__ int csP[32], csQ[32];
  __shared__ double evals[64]; __shared__ int idxs[64];
  __shared__ double red[4];
  int q=ru;
  for(int e=tid;e<q*q;e+=256){
    int a=e/q,b=e%q;
    K[a*LDK+b]=0.5*(S[(size_t)a*q+b]+S[(size_t)b*q+a]);
    W[a*LDK+b]=(a==b)?1.f:0.f;
  }
  __syncthreads();
  dev_jacobi(K,W,q,tid,8,csC,csS,csP,csQ);
  dev_select(K,q,keep,tid,evals,idxs);
  for(int e=tid;e<ru*keep;e+=256){
    int col=e/keep, j=e%keep;
    V[e]=(double)W[col*LDK+idxs[j]];
  }
  __syncthreads();
  dev_orthV(V,ru,keep,red);
  for(int e=tid;e<keep*ru;e+=256){
    int j=e/ru, col=e%ru;
    NM[e]=V[(size_t)col*keep+j];
  }
  for(int e=tid;e<l*keep;e+=256){
    int i=e/keep, j=e%keep;
    const double* Mi=MP+(size_t)i*ru;
    double acc=0.0;
    for(int c=0;c<ru;c++) acc+=Mi[c]*V[(size_t)c*keep+j];
    C[e]=acc;
  }
}

// ---------------------------------------------------------------------------
// Yout = sinv * S * Yin  (512 threads: row i = tid&255, col-half = tid>>8)
__device__ void dev_smul(const double* S, const double* Yin, double* Yout,
                         double* Yt, double sinv, int tid){
  double acc[32];
  int i=tid&255, j0=(tid>>8)*32;
  #pragma unroll
  for(int j=0;j<32;j++) acc[j]=0.0;
  for(int cb=0;cb<16;cb++){
    __syncthreads();
    for(int e=tid;e<1024;e+=512) Yt[e]=Yin[cb*1024+e];
    __syncthreads();
    const double* Srow=S+(size_t)i*256+cb*16;
    for(int c=0;c<16;c++){
      double sv=Srow[c];
      const double* Yr=Yt+c*64+j0;
      #pragma unroll
      for(int j=0;j<32;j++) acc[j]+=sv*Yr[j];
    }
  }
  #pragma unroll
  for(int j=0;j<32;j++) Yout[(size_t)i*64+j0+j]=acc[j]*sinv;
  __syncthreads();
}

// ---------------------------------------------------------------------------
// SHIFTED CholeskyQR on Yg (256 x ncols, f64 global), 512 threads.
// Gram+lam*I = R^T R (upper in Kd, stride LDK); Ri=R^{-1} in LDS; X=Y*Ri as
// staged GEMM. Pivots >= lam/4: overflow-free.
__device__ void dev_cholqr(double* Yg, int ncols, double* Kd, double* Yt,
                           double* Ri, double* shv, int tid){
  int rpb=1024/ncols, nblk=256/rpb, n2=ncols*ncols;
  for(int e=tid;e<n2;e+=512) Kd[(e/ncols)*LDK+(e%ncols)]=0.0;
  for(int b=0;b<nblk;b++){
    __syncthreads();
    for(int e=tid;e<1024;e+=512) Yt[e]=Yg[b*1024+e];
    __syncthreads();
    for(int e=tid;e<n2;e+=512){
      int a=e/ncols, c=e%ncols;
      if(c>=a){
        double acc=0.0;
        for(int r=0;r<rpb;r++) acc+=Yt[r*ncols+a]*Yt[r*ncols+c];
        Kd[a*LDK+c]+=acc;
      }
    }
  }
  __syncthreads();
  if(tid==0){
    double tr=0.0;
    for(int j=0;j<ncols;j++) tr+=Kd[j*LDK+j];
    shv[0]=(tr/ncols)*1e-14+1e-290;
  }
  __syncthreads();
  double lam=shv[0];
  for(int i=tid;i<ncols;i+=512) Kd[i*LDK+i]+=lam;
  __syncthreads();
  for(int j=0;j<ncols;j++){
    double d=Kd[j*LDK+j];
    if(!(d>lam*0.25)) d=lam*0.25;
    double invd=1.0/d;
    if(tid==0) Kd[j*LDK+j]=d;
    int w=ncols-1-j;
    for(int e=tid;e<w*w;e+=512){
      int i2=j+1+e/w, k2=j+1+e%w;
      if(k2>=i2) Kd[i2*LDK+k2]-=Kd[j*LDK+i2]*Kd[j*LDK+k2]*invd;
    }
    __syncthreads();
  }
  for(int i=tid;i<ncols;i+=512) Yt[i]=1.0/sqrt(Kd[i*LDK+i]);
  __syncthreads();
  for(int e=tid;e<n2;e+=512){
    int i=e/ncols, k=e%ncols;
    if(k>=i) Kd[i*LDK+k]*=Yt[i];
  }
  __syncthreads();
  if(tid<ncols){
    int j=tid;
    Ri[j*66+j]=1.0/Kd[j*LDK+j];
    for(int i=j-1;i>=0;i--){
      double s=0.0;
      for(int k=i+1;k<=j;k++) s+=Kd[i*LDK+k]*Ri[k*66+j];
      Ri[i*66+j]=-s/Kd[i*LDK+i];
    }
  }
  __syncthreads();
  {
    int j=tid%ncols, rg=tid/ncols;   // groups=512/ncols, 2 rows/thread
    for(int b=0;b<nblk;b++){
      for(int e=tid;e<1024;e+=512) Yt[e]=Yg[b*1024+e];
      __syncthreads();
      double xr[2];
      #pragma unroll
      for(int r4=0;r4<2;r4++){
        int r=rg*2+r4;
        double acc=0.0;
        for(int k=0;k<=j;k++) acc+=Yt[r*ncols+k]*Ri[k*66+j];
        xr[r4]=acc;
      }
      __syncthreads();
      #pragma unroll
      for(int r4=0;r4<2;r4++){
        int r=rg*2+r4;
        Yg[(size_t)b*1024 + r*ncols + j]=xr[r4];
      }
    }
  }
  __syncthreads();
}

// subspace path (ru==256): degree-2 power iteration x10 (QR1 per pair, QR2 at
// rounds 5/10), Ritz via Jacobi, f64 V re-orth. 512 threads.
__global__ __launch_bounds__(512,1)
void k_eig_sub(double* ws, int Soff, int MPoff, int l, int keep,
               int newoff, int Coff){
  const int RU=256;
  int tid=threadIdx.x;
  double* base=ws+(size_t)blockIdx.z*SAMP_J;
  const double* S=base+Soff;
  const double* MP=base+MPoff;
  double* Ya=base+O_Y;
  double* Yb=base+O_Y2;
  double* V =base+O_V;
  double* C =base+Coff;
  double* NM=base+newoff;
  __shared__ double Kd[64*LDK];    // 33.3 KB
  __shared__ double Ri[64*66];     // 33.8 KB
  __shared__ float  Wf[64*LDK];    // 16.6 KB
  __shared__ double Yt[1024];      // 8 KB
  __shared__ double red[516];
  __shared__ unsigned long long om[256];
  __shared__ double csC[32], csS[32];
  __shared__ int csP[32], csQ[32];
  __shared__ double evals[64]; __shared__ int idxs[64];

  // sinv = 1/max diag(S)
  double mx=0.0;
  for(int i=tid;i<RU;i+=512) mx=fmax(mx,S[(size_t)i*RU+i]);
  red[tid]=mx; __syncthreads();
  for(int w=256;w>0;w>>=1){ if(tid<w) red[tid]=fmax(red[tid],red[tid+w]); __syncthreads(); }
  double sinv=(red[0]>0.0)?1.0/red[0]:1.0;
  __syncthreads();

  // Omega sign table
  for(int c2=tid;c2<256;c2+=512){
    unsigned long long mask=0ull;
    for(int j=0;j<64;j++){
      unsigned h=(unsigned)(c2*1103515245u)^(unsigned)((j+1)*2654435761u);
      h^=h>>13; h*=0x9E3779B1u;
      mask |= ((unsigned long long)((h>>16)&1u))<<j;
    }
    om[c2]=mask;
  }
  __syncthreads();

  // Ya = sinv * S * Omega
  for(int e=tid;e<RU*64;e+=512){
    int i=e>>6, j=e&63;
    const double* Si=S+(size_t)i*RU;
    double acc=0.0;
    for(int c2=0;c2<RU;c2++)
      acc += ((om[c2]>>j)&1ull)? Si[c2] : -Si[c2];
    Ya[e]=acc*sinv;
  }
  __syncthreads();
  dev_cholqr(Ya,64,Kd,Yt,Ri,red+512,tid);
  dev_cholqr(Ya,64,Kd,Yt,Ri,red+512,tid);
  for(int it=0;it<10;it++){
    dev_smul(S,Ya,Yb,Yt,sinv,tid);
    dev_smul(S,Yb,Ya,Yt,sinv,tid);
    dev_cholqr(Ya,64,Kd,Yt,Ri,red+512,tid);
    if(it==4||it==9) dev_cholqr(Ya,64,Kd,Yt,Ri,red+512,tid);
  }
  dev_smul(S,Ya,Yb,Yt,sinv,tid);     // Yb = S*Ya (unorthogonalized)

  // Ritz: K = Ya^T Yb
  for(int e=tid;e<4096;e+=512){ int a=e>>6,c=e&63; Kd[a*LDK+c]=0.0; }
  for(int b=0;b<32;b++){
    __syncthreads();
    { int e=tid; Yt[e]=Ya[b*512+e]; /* 512 threads cover 512 */ }
    { int e=tid; Yt[512+e]=Yb[b*512+e]; }
    __syncthreads();
    for(int i=0;i<8;i++){
      int idx=tid*8+i; int a=idx>>6, c=idx&63;
      double acc=Kd[a*LDK+c];
      for(int r=0;r<8;r++) acc+=Yt[r*64+a]*Yt[512+r*64+c];
      Kd[a*LDK+c]=acc;
    }
  }
  __syncthreads();
  for(int e=tid;e<4096;e+=512){
    int a=e>>6,c=e&63;
    if(a<c){ double m=0.5*(Kd[a*LDK+c]+Kd[c*LDK+a]); Kd[a*LDK+c]=m; Kd[c*LDK+a]=m; }
  }
  __syncthreads();
  for(int e=tid;e<4096;e+=512){ int a=e>>6,c=e&63; Wf[a*LDK+c]=(a==c)?1.f:0.f; }
  __syncthreads();
  dev_jacobi(Kd,Wf,64,tid,6,csC,csS,csP,csQ);
  dev_select(Kd,64,keep,tid,evals,idxs);
  // V = Ya * W[:,sel]
  for(int e=tid;e<RU*keep;e+=512){
    int i=e/keep, j=e%keep; int vj=idxs[j];
    const double* Yr=Ya+(size_t)i*64;
    double acc=0.0;
    for(int t=0;t<64;t++) acc+=Yr[t]*(double)Wf[t*LDK+vj];
    V[e]=acc;
  }
  __syncthreads();
  dev_cholqr(V,keep,Kd,Yt,Ri,red+512,tid);   // f64 exact-projector fix
  for(int e=tid;e<keep*RU;e+=512){
    int j=e/RU, col=e%RU;
    NM[e]=V[(size_t)col*keep+j];
  }
  for(int e=tid;e<l*keep;e+=512){
    int i=e/keep, j=e%keep;
    const double* Mi=MP+(size_t)i*RU;
    double acc=0.0;
    for(int col=0;col<RU;col++) acc+=Mi[col]*V[(size_t)col*keep+j];
    C[e]=acc;
  }
}

// ---------------------------------------------------------------------------
__global__ void k_copy(double* ws){
  double* base=ws+(size_t)blockIdx.z*SAMP_J;
  for(int e=blockIdx.x*blockDim.x+threadIdx.x;e<65536;e+=gridDim.x*blockDim.x)
    base[O_CUR+e]=base[O_NEW+e];
}

__global__ __launch_bounds__(256)
void k_final(double* ws, float* out, int s0){
  int z=blockIdx.z, tid=threadIdx.x;
  const double* bot=ws+(size_t)(2*z)*SAMP_J+O_CUR;
  const double* top=ws+(size_t)(2*z+1)*SAMP_J+O_CUR;
  __shared__ double v[1024], v2[1024];
  __shared__ float w[8192];
  const int Bf[9]={1,8,32,32,32,32,32,8,1};
  if(tid==0) v[0]=1.0;
  __syncthreads();
  for(int y=0;y<8;y++){
    int a=Bf[y], b=Bf[y+1];
    const double* By=bot+y*8192;
    const double* Ty=top+y*8192;
    for(int e=tid;e<a*b*8;e+=256){
      int k2=e&7; int bb=(e>>3)%b; int cc=e/(8*b);
      double acc=0.0;
      for(int aa=0;aa<a;aa++) acc+=v[aa*a+cc]*By[(aa*b+bb)*8+k2];
      w[(cc*b+bb)*8+k2]=(float)acc;
    }
    __syncthreads();
    for(int e=tid;e<b*b;e+=256){
      int dd=e%b; int bb=e/b;
      double acc=0.0;
      for(int cc=0;cc<a;cc++)
        for(int k2=0;k2<8;k2++)
          acc+=(double)w[(cc*b+bb)*8+k2]*Ty[(cc*b+dd)*8+k2];
      v2[bb*b+dd]=acc;
    }
    __syncthreads();
    for(int e=tid;e<b*b;e+=256) v[e]=v2[e];
    __syncthreads();
  }
  if(tid==0) out[s0+z]=(float)v[0];
}

// ---------------------------------------------------------------------------
static void run_compress_dual(double* ws, const float* peps, const int* x,
                              int s0, int ns, int xib, int xit, bool first,
                              hipStream_t stream){
  int njobs=2*ns;
  int Bin[9]; Bin[0]=1; Bin[8]=1;
  for(int i=1;i<8;i++) Bin[i]= first?8:((i==1||i==7)?8:32);
  int lraw[8], rraw[8];
  for(int y=0;y<8;y++){ lraw[y]=Bin[y]*((y>0)?8:1); rraw[y]=Bin[y+1]*((y<7)?8:1); }
  int kch[8];
  { int kp=1;
    for(int y=0;y<8;y++){ int n=(y<7)?Bin[y+1]*8:1; kch[y]=imin_(kp*8,n); kp=kch[y]; } }
  int keep[8];
  keep[7]=imin_(32, imin_(kch[6], 8));
  for(int y=6;y>=1;y--) keep[y]=imin_(32, imin_(kch[y-1], keep[y+1]*8));

  // forward: G^(1..7)
  for(int y=0;y<7;y++){
    k_absorb<<<dim3(Bin[y+1],1,njobs),256,0,stream>>>(ws,peps,x,s0,xib,xit,y,Bin[y],Bin[y+1]);
    int l=lraw[y], r8=rraw[y]*8;
    k_mmGT<<<dim3((l+15)/16,(r8+15)/16,njobs),dim3(16,16),0,stream>>>(
        ws,O_GSB+goff[y],O_TF,O_H2F,l,l,r8);
    k_gacc2<<<dim3(rraw[y]/16,rraw[y]/16,njobs),dim3(16,16),0,stream>>>(
        ws,O_H2F,O_TF,O_GSB+goff[y+1],l,rraw[y]);
    k_gscale<<<dim3(1,1,njobs),256,0,stream>>>(ws,O_GSB+goff[y+1],rraw[y]);
  }
  // backward
  for(int y=7;y>=1;y--){
    k_absorb<<<dim3(Bin[y+1],1,njobs),256,0,stream>>>(ws,peps,x,s0,xib,xit,y,Bin[y],Bin[y+1]);
    int ru=(y==7)?8:keep[y+1]*8;
    if(y==7) k_t2mp<<<dim3(2,1,njobs),256,0,stream>>>(ws,lraw[7]*8);
    else     k_mp<<<dim3(lraw[y],1,njobs),256,0,stream>>>(ws,O_TF,O_C,O_MP,rraw[y],keep[y+1]);
    int l=lraw[y];
    k_mm<<<dim3((l+15)/16,(ru+15)/16,njobs),dim3(16,16),0,stream>>>(
        ws,O_GSB+goff[y],O_MP,O_H,l,l,ru);
    k_mm_tn<<<dim3((ru+15)/16,(ru+15)/16,njobs),dim3(16,16),0,stream>>>(
        ws,O_MP,O_H,O_S,ru,l,ru);
    if(ru<=64)
      k_eig_direct<<<dim3(1,1,njobs),256,0,stream>>>(ws,O_S,O_MP,l,ru,keep[y],
                    O_NEW+y*8192,O_C);
    else
      k_eig_sub<<<dim3(1,1,njobs),512,0,stream>>>(ws,O_S,O_MP,l,keep[y],
                    O_NEW+y*8192,O_C);
  }
  // site 0
  k_absorb<<<dim3(Bin[1],1,njobs),256,0,stream>>>(ws,peps,x,s0,xib,xit,0,1,Bin[1]);
  k_mp<<<dim3(1,1,njobs),256,0,stream>>>(ws,O_TF,O_C,O_NEW+0,rraw[0],keep[1]);
  k_copy<<<dim3(32,1,njobs),256,0,stream>>>(ws);
}

extern "C" void kernel_launch(void* const* d_in, const int* in_sizes, int n_in,
                              void* d_out, int out_size, void* d_ws, size_t ws_size,
                              hipStream_t stream){
  const int*   x    = (const int*)d_in[0];     // (16,64) int32
  const float* peps = (const float*)d_in[1];   // (8,8,8,8,8,8,2) f32
  float* out = (float*)d_out;                  // 16 f32
  double* ws = (double*)d_ws;
  size_t samp_bytes = (size_t)2*SAMP_J*sizeof(double);
  int max_chunk=(int)(ws_size/samp_bytes);
  if(max_chunk<1) max_chunk=1;
  if(max_chunk>16) max_chunk=16;
  for(int s0=0;s0<16;s0+=max_chunk){
    int ns=imin_(max_chunk,16-s0);
    int njobs=2*ns;
    k_init_row<<<dim3(8,1,njobs),64,0,stream>>>(ws,peps,x,s0);
    run_compress_dual(ws,peps,x,s0,ns,1,6,true ,stream);
    run_compress_dual(ws,peps,x,s0,ns,2,5,false,stream);
    run_compress_dual(ws,peps,x,s0,ns,3,4,false,stream);
    k_final<<<dim3(1,1,ns),256,0,stream>>>(ws,out,s0);
  }
}

// Round 8
// 91079.730 us; speedup vs baseline: 14.6380x; 1.6969x over previous
//
#include <hip/hip_runtime.h>

// ---------------------------------------------------------------------------
// fPEPS amplitude via boundary-MPS, chi=32. Metric ("left-Gram") formulation,
// f64 core with f32 bulk-tensor storage. Truncation = top eigvecs of M'^T G M'
// via in-LDS SHIFTED CholeskyQR subspace iteration (overflow-free, f64).
// Bottom & top chains fused per launch (blockIdx.z = sample*2+side).
// Lx=Ly=8, D=8, P=2, CHI=32.
//
// R1: cholqr solve -> in-LDS Rinv + staged GEMM. R2: schedule+workspace slim
// (single chunk, 16 samples resident). R4: 512-thread eig_sub, LDK=65 bank
// fix, degree-2 schedule, parallel select (327k->154.5k us, verified).
// R7 (this): move matrix-power FLOPs off the 32 single-block eig_sub kernels
// onto the whole machine — S2=S*S and S4=S2*S2 precomputed by batched k_mm
// (8192 blocks); eig_sub loop becomes 4x{Y=S4*Y; QR1} (S^20 filter
// unchanged). smuls 21->5(+init), cholqr 14->8, eig FLOPs 240->~90 MF/job.
// sinv scaling removed (CholQR renormalizes; f64 range safe).
// Fallback if absmax regresses: S2 with 10x{Y=S2*Y; QR1} (R4-equivalent).
// ---------------------------------------------------------------------------

__host__ __device__ static inline int imin_(int a,int b){return a<b?a:b;}

static constexpr int SAMP_J = 991296;    // 7.93 MB/job
static constexpr int O_CUR = 0;
static constexpr int O_NEW = 65536;
static constexpr int O_TF  = 131072;
static constexpr int O_H2F = 393216;
static constexpr int O_MP  = 393216;
static constexpr int O_H   = 458752;     // H = G*M'; dead after k_mm_tn -> S2 temp
static constexpr int O_S   = 524288;
static constexpr int O_Y   = 589824;
static constexpr int O_Y2  = 606208;
static constexpr int O_C   = 622592;
static constexpr int O_V   = 630784;
static constexpr int O_GSB = 655360;
// G^(6) slot (goff[6], 65536 doubles): consumed before any eig_sub in the
// backward sweep -> reused as S4 storage.
static constexpr int O_S4  = O_GSB + 266241;

static const int goff[8] = {0,1,4097,69633,135169,200705,266241,331777};

// LDS row stride for 64x64 matrices (bank-conflict padding)
#define LDK 65

// ---------------------------------------------------------------------------
__global__ void k_init_row(double* ws, const float* peps, const int* x, int s0){
  int z=blockIdx.z, y=blockIdx.x;
  int side=z&1, samp=z>>1;
  int xi = side?7:0;
  double* base = ws + (size_t)z*SAMP_J;
  double* cur = base + O_CUR + y*8192;
  int spin = x[(s0+samp)*64 + xi*8 + y];
  const float* pb = peps + (size_t)xi*65536 + (size_t)y*8192 + spin;
  int rd=(y<7)?8:1, ld=(y>0)?8:1;
  int ntot = ld*rd*8;
  for(int e=threadIdx.x; e<ntot; e+=blockDim.x){
    int u=e&7; int r=(e>>3)%rd; int l=e/(8*rd);
    float v = side ? pb[u*128 + l*16 + r*2] : pb[u*1024 + l*16 + r*2];
    cur[e]=(double)v;
  }
  if(y==0 && threadIdx.x==0) base[O_GSB]=1.0;
}

// ---------------------------------------------------------------------------
__global__ __launch_bounds__(256)
void k_absorb(double* ws, const float* peps, const int* x, int s0,
              int xi_b, int xi_t, int y, int bl, int brdim){
  int z=blockIdx.z, yb=blockIdx.x;
  int side=z&1, samp=z>>1;
  int xi = side? xi_t : xi_b;
  int so = side? 128:1024, sc = side? 1024:128;
  double* base=ws+(size_t)z*SAMP_J;
  const double* B=base+O_CUR+y*8192;
  float* T=(float*)(base+O_TF);
  int spin=x[(s0+samp)*64+xi*8+y];
  const float* A=peps+(size_t)xi*65536+(size_t)y*8192+spin;
  int Lp=(y>0)?8:1, Rp=(y<7)?8:1;
  int rraw=brdim*Rp;
  __shared__ float As[4096];
  __shared__ double Bs[256];
  int nA=64*Lp*Rp;
  for(int e=threadIdx.x;e<nA;e+=256){
    int rp=e%Rp; int t=e/Rp; int lp=t%Lp; t/=Lp; int p=t&7; int u=t>>3;
    As[e]=A[u*so+p*sc+lp*16+rp*2];
  }
  for(int e=threadIdx.x;e<bl*8;e+=256)
    Bs[e]=B[((e>>3)*brdim+yb)*8+(e&7)];
  __syncthreads();
  int ntot=bl*Lp*Rp*8;
  for(int e=threadIdx.x;e<ntot;e+=256){
    int u=e&7; int t=e>>3; int rp=t%Rp; t/=Rp; int lp=t%Lp; int xx=t/Lp;
    double acc=0.0;
    #pragma unroll
    for(int p=0;p<8;p++) acc+=Bs[xx*8+p]*(double)As[((u*8+p)*Lp+lp)*Rp+rp];
    T[(size_t)((xx*Lp+lp)*rraw + yb*Rp+rp)*8 + u]=(float)acc;
  }
}

// ---------------------------------------------------------------------------
__global__ void k_mmGT(double* ws, int Aoff, int Boff, int Coff, int ni, int nk, int nj){
  double* base=ws+(size_t)blockIdx.z*SAMP_J;
  const double* A=base+Aoff;
  const float* B=(const float*)(base+Boff);
  float* C=(float*)(base+Coff);
  __shared__ double As[16][17]; __shared__ float Bs[16][17];
  int tx=threadIdx.x, ty=threadIdx.y;
  int i0=blockIdx.x*16, j0=blockIdx.y*16;
  double acc=0.0;
  for(int k0=0;k0<nk;k0+=16){
    As[ty][tx]=(i0+ty<ni && k0+tx<nk)? A[(size_t)(i0+ty)*nk + k0+tx] : 0.0;
    Bs[ty][tx]=(k0+ty<nk && j0+tx<nj)? B[(size_t)(k0+ty)*nj + j0+tx] : 0.f;
    __syncthreads();
    #pragma unroll
    for(int t=0;t<16;t++) acc+=As[ty][t]*(double)Bs[t][tx];
    __syncthreads();
  }
  if(i0+ty<ni && j0+tx<nj) C[(size_t)(i0+ty)*nj + j0+tx]=(float)acc;
}

__global__ void k_mm(double* ws, int Aoff, int Boff, int Coff, int ni, int nk, int nj){
  double* base=ws+(size_t)blockIdx.z*SAMP_J;
  const double* A=base+Aoff; const double* B=base+Boff; double* C=base+Coff;
  __shared__ double As[16][17], Bs[16][17];
  int tx=threadIdx.x, ty=threadIdx.y;
  int i0=blockIdx.x*16, j0=blockIdx.y*16;
  double acc=0.0;
  for(int k0=0;k0<nk;k0+=16){
    As[ty][tx]=(i0+ty<ni && k0+tx<nk)? A[(size_t)(i0+ty)*nk + k0+tx] : 0.0;
    Bs[ty][tx]=(k0+ty<nk && j0+tx<nj)? B[(size_t)(k0+ty)*nj + j0+tx] : 0.0;
    __syncthreads();
    #pragma unroll
    for(int t=0;t<16;t++) acc+=As[ty][t]*Bs[t][tx];
    __syncthreads();
  }
  if(i0+ty<ni && j0+tx<nj) C[(size_t)(i0+ty)*nj + j0+tx]=acc;
}
__global__ void k_mm_tn(double* ws, int Aoff, int Boff, int Coff, int ni, int nk, int nj){
  double* base=ws+(size_t)blockIdx.z*SAMP_J;
  const double* A=base+Aoff; const double* B=base+Boff; double* C=base+Coff;
  __shared__ double As[16][17], Bs[16][17];
  int tx=threadIdx.x, ty=threadIdx.y;
  int i0=blockIdx.x*16, j0=blockIdx.y*16;
  double acc=0.0;
  for(int k0=0;k0<nk;k0+=16){
    As[ty][tx]=(k0+ty<nk && i0+tx<ni)? A[(size_t)(k0+ty)*ni + i0+tx] : 0.0;
    Bs[ty][tx]=(k0+ty<nk && j0+tx<nj)? B[(size_t)(k0+ty)*nj + j0+tx] : 0.0;
    __syncthreads();
    #pragma unroll
    for(int t=0;t<16;t++) acc+=As[t][ty]*Bs[t][tx];
    __syncthreads();
  }
  if(i0+ty<ni && j0+tx<nj) C[(size_t)(i0+ty)*nj + j0+tx]=acc;
}

// ---------------------------------------------------------------------------
__global__ void k_gacc2(double* ws, int H2off, int Toff, int Goff, int ldim, int rdim){
  int bx=blockIdx.x, by=blockIdx.y;
  if(by<bx) return;
  double* base=ws+(size_t)blockIdx.z*SAMP_J;
  const float* H2=(const float*)(base+H2off);
  const float* T=(const float*)(base+Toff);
  double* G=base+Goff;
  __shared__ float As[16][17], Bs[16][17];
  int tx=threadIdx.x, ty=threadIdx.y;
  int r0=bx*16, r1=by*16;
  double acc=0.0;
  int ktot=ldim*8;
  for(int k0=0;k0<ktot;k0+=16){
    int kk=k0+ty; int l2=kk>>3; int u=kk&7;
    As[ty][tx]=(kk<ktot)? H2[((size_t)l2*rdim + r0+tx)*8 + u] : 0.f;
    Bs[ty][tx]=(kk<ktot)? T [((size_t)l2*rdim + r1+tx)*8 + u] : 0.f;
    __syncthreads();
    #pragma unroll
    for(int t=0;t<16;t++) acc+=(double)As[t][ty]*(double)Bs[t][tx];
    __syncthreads();
  }
  G[(size_t)(r0+ty)*rdim + r1+tx]=acc;
  if(by>bx) G[(size_t)(r1+tx)*rdim + r0+ty]=acc;
}

__global__ void k_gscale(double* ws, int Goff, int n){
  int tid=threadIdx.x;
  double* base=ws+(size_t)blockIdx.z*SAMP_J;
  double* G=base+Goff;
  __shared__ double red[256]; __shared__ double s_sc;
  double mx=0.0;
  for(int i=tid;i<n;i+=256) mx=fmax(mx,fabs(G[(size_t)i*n+i]));
  red[tid]=mx; __syncthreads();
  for(int w=128;w>0;w>>=1){ if(tid<w) red[tid]=fmax(red[tid],red[tid+w]); __syncthreads(); }
  if(tid==0) s_sc=(red[0]>0.0)?1.0/red[0]:1.0;
  __syncthreads();
  double sc=s_sc;
  for(int e=tid;e<n*n;e+=256) G[e]*=sc;
}

// ---------------------------------------------------------------------------
__global__ __launch_bounds__(256)
void k_mp(double* ws, int Toff, int Coff, int Moff, int rraw, int keep){
  int li=blockIdx.x, tid=threadIdx.x;
  double* base=ws+(size_t)blockIdx.z*SAMP_J;
  const float* T=(const float*)(base+Toff) + (size_t)li*rraw*8;
  const double* Cc=base+Coff;
  double* M=base+Moff+(size_t)li*keep*8;
  __shared__ float Ts[2048];
  for(int e=tid;e<rraw*8;e+=256) Ts[e]=T[e];
  __syncthreads();
  for(int e=tid;e<keep*8;e+=256){
    int u=e&7, k=e>>3;
    double acc=0.0;
    for(int r=0;r<rraw;r++) acc+=(double)Ts[r*8+u]*Cc[(size_t)r*keep+k];
    M[k*8+u]=acc;
  }
}

__global__ void k_t2mp(double* ws, int n){
  double* base=ws+(size_t)blockIdx.z*SAMP_J;
  const float* T=(const float*)(base+O_TF);
  for(int e=blockIdx.x*blockDim.x+threadIdx.x;e<n;e+=gridDim.x*blockDim.x)
    base[O_MP+e]=(double)T[e];
}

// ---------------------------------------------------------------------------
// Cyclic Jacobi, closed-form round-robin (circle method). Matrices at LDS
// stride LDK(=65). NT-agnostic (uses blockDim.x). 3 barriers/round.
__device__ void dev_jacobi(double* K, float* W, int q, int tid, int sweeps,
                           double* csC, double* csS, int* csP, int* csQ){
  int NT=blockDim.x;
  int m=q-1, npairs=q>>1;
  int L=NT/npairs;
  int inv2=(m+1)>>1;
  for(int sweep=0;sweep<sweeps;sweep++)
  for(int rnd=0;rnd<m;rnd++){
    if(tid<npairs){
      int i0=(int)(((long long)rnd*(long long)inv2)%m);
      int p,qq;
      if(tid==0){ p=i0; qq=q-1; }
      else {
        p=i0+tid; if(p>=m) p-=m;
        qq=i0-tid; if(qq<0) qq+=m;
      }
      if(p>qq){int t=p;p=qq;qq=t;}
      double c=1.0,s2=0.0;
      double apq=K[p*LDK+qq];
      double app=K[p*LDK+p], aqq=K[qq*LDK+qq];
      if(fabs(apq) > 1e-18*(fabs(app)+fabs(aqq))+1e-300){
        double tau=(aqq-app)/(2.0*apq);
        double t=(tau>=0.0?1.0:-1.0)/(fabs(tau)+sqrt(1.0+tau*tau));
        c=1.0/sqrt(1.0+t*t); s2=t*c;
      }
      csP[tid]=p; csQ[tid]=qq; csC[tid]=c; csS[tid]=s2;
    }
    __syncthreads();
    int pr=tid/L, lane=tid%L;
    {
      int p=csP[pr], qq=csQ[pr];
      double c=csC[pr], s2=csS[pr];
      for(int j=lane;j<q;j+=L){
        double kp=K[p*LDK+j], kq=K[qq*LDK+j];
        K[p*LDK+j]=c*kp-s2*kq; K[qq*LDK+j]=s2*kp+c*kq;
      }
    }
    __syncthreads();
    {
      int p=csP[pr], qq=csQ[pr];
      double c=csC[pr], s2=csS[pr];
      float cf=(float)c, sf=(float)s2;
      for(int j=lane;j<q;j+=L){
        double kp=K[j*LDK+p], kq=K[j*LDK+qq];
        K[j*LDK+p]=c*kp-s2*kq; K[j*LDK+qq]=s2*kp+c*kq;
        float wp=W[j*LDK+p], wq=W[j*LDK+qq];
        W[j*LDK+p]=cf*wp-sf*wq; W[j*LDK+qq]=sf*wp+cf*wq;
      }
    }
    __syncthreads();
  }
}

// parallel top-keep select: wave-0 argmax per pick (no serial LDS chain)
__device__ void dev_select(const double* K, int q, int keep, int tid,
                           double* evals, int* idxs){
  for(int a=tid;a<q;a+=blockDim.x) evals[a]=K[a*LDK+a];
  __syncthreads();
  if(tid<64){
    int a=tid;
    double v=(a<q)? evals[a] : -1.0e300;
    for(int j=0;j<keep;j++){
      double bv=v; int bi=a;
      for(int off=1;off<64;off<<=1){
        double ov=__shfl_xor(bv,off); int oi=__shfl_xor(bi,off);
        if(ov>bv || (ov==bv && oi<bi)){ bv=ov; bi=oi; }
      }
      if(a==bi) v=-1.0e300;
      if(tid==0) idxs[j]=bi;
    }
  }
  __syncthreads();
}

// f64 CGS2 of V columns (n rows, keep cols, row-major stride keep) [256 thr]
__device__ void dev_orthV(double* V, int n, int keep, double* red){
  int tid=threadIdx.x;
  for(int j=0;j<keep;j++){
    double vj=(tid<n)? V[(size_t)tid*keep+j] : 0.0;
    for(int pass=0;pass<2;pass++){
      for(int t=0;t<j;t++){
        double vt=(tid<n)? V[(size_t)tid*keep+t] : 0.0;
        double p=vj*vt;
        for(int off=1;off<64;off<<=1) p+=__shfl_xor(p,off);
        if((tid&63)==0) red[tid>>6]=p;
        __syncthreads();
        double d=red[0]+red[1]+red[2]+red[3];
        vj-=d*vt;
        __syncthreads();
      }
    }
    double p=vj*vj;
    for(int off=1;off<64;off<<=1) p+=__shfl_xor(p,off);
    if((tid&63)==0) red[tid>>6]=p;
    __syncthreads();
    double nrm=red[0]+red[1]+red[2]+red[3];
    vj=vj/sqrt(fmax(nrm,1e-300));
    if(tid<n) V[(size_t)tid*keep+j]=vj;
    __syncthreads();
  }
}

// ---------------------------------------------------------------------------
// direct path (ru<=64), 256 threads
__global__ __launch_bounds__(256)
void k_eig_direct(double* ws, int Soff, int MPoff, int l, int ru, int keep,
                  int newoff, int Coff){
  int tid=threadIdx.x;
  double* base=ws+(size_t)blockIdx.z*SAMP_J;
  const double* S=base+Soff;
  const double* MP=base+MPoff;
  double* C=base+Coff;
  double* NM=base+newoff;
  double* V=base+O_V;
  __shared__ double K[64*LDK];
  __shared__ float W[64*LDK];
  __shared__ double csC[32], csS[32];
  __shared__ int csP[32], csQ[32];
  __shared__ double evals[64]; __shared__ int idxs[64];
  __shared__ double red[4];
  int q=ru;
  for(int e=tid;e<q*q;e+=256){
    int a=e/q,b=e%q;
    K[a*LDK+b]=0.5*(S[(size_t)a*q+b]+S[(size_t)b*q+a]);
    W[a*LDK+b]=(a==b)?1.f:0.f;
  }
  __syncthreads();
  dev_jacobi(K,W,q,tid,8,csC,csS,csP,csQ);
  dev_select(K,q,keep,tid,evals,idxs);
  for(int e=tid;e<ru*keep;e+=256){
    int col=e/keep, j=e%keep;
    V[e]=(double)W[col*LDK+idxs[j]];
  }
  __syncthreads();
  dev_orthV(V,ru,keep,red);
  for(int e=tid;e<keep*ru;e+=256){
    int j=e/ru, col=e%ru;
    NM[e]=V[(size_t)col*keep+j];
  }
  for(int e=tid;e<l*keep;e+=256){
    int i=e/keep, j=e%keep;
    const double* Mi=MP+(size_t)i*ru;
    double acc=0.0;
    for(int c=0;c<ru;c++) acc+=Mi[c]*V[(size_t)c*keep+j];
    C[e]=acc;
  }
}

// ---------------------------------------------------------------------------
// Yout = A * Yin  (A 256x256 f64 global; Y 256x64 f64 global)
// 512 threads: row i = tid&255, col-half = tid>>8
__device__ void dev_smul(const double* A, const double* Yin, double* Yout,
                         double* Yt, int tid){
  double acc[32];
  int i=tid&255, j0=(tid>>8)*32;
  #pragma unroll
  for(int j=0;j<32;j++) acc[j]=0.0;
  for(int cb=0;cb<16;cb++){
    __syncthreads();
    for(int e=tid;e<1024;e+=512) Yt[e]=Yin[cb*1024+e];
    __syncthreads();
    const double* Arow=A+(size_t)i*256+cb*16;
    for(int c=0;c<16;c++){
      double sv=Arow[c];
      const double* Yr=Yt+c*64+j0;
      #pragma unroll
      for(int j=0;j<32;j++) acc[j]+=sv*Yr[j];
    }
  }
  #pragma unroll
  for(int j=0;j<32;j++) Yout[(size_t)i*64+j0+j]=acc[j];
  __syncthreads();
}

// ---------------------------------------------------------------------------
// SHIFTED CholeskyQR on Yg (256 x ncols, f64 global), 512 threads.
// Gram+lam*I = R^T R (upper in Kd, stride LDK); Ri=R^{-1} in LDS; X=Y*Ri as
// staged GEMM. Pivots >= lam/4: overflow-free.
__device__ void dev_cholqr(double* Yg, int ncols, double* Kd, double* Yt,
                           double* Ri, double* shv, int tid){
  int rpb=1024/ncols, nblk=256/rpb, n2=ncols*ncols;
  for(int e=tid;e<n2;e+=512) Kd[(e/ncols)*LDK+(e%ncols)]=0.0;
  for(int b=0;b<nblk;b++){
    __syncthreads();
    for(int e=tid;e<1024;e+=512) Yt[e]=Yg[b*1024+e];
    __syncthreads();
    for(int e=tid;e<n2;e+=512){
      int a=e/ncols, c=e%ncols;
      if(c>=a){
        double acc=0.0;
        for(int r=0;r<rpb;r++) acc+=Yt[r*ncols+a]*Yt[r*ncols+c];
        Kd[a*LDK+c]+=acc;
      }
    }
  }
  __syncthreads();
  if(tid==0){
    double tr=0.0;
    for(int j=0;j<ncols;j++) tr+=Kd[j*LDK+j];
    shv[0]=(tr/ncols)*1e-14+1e-290;
  }
  __syncthreads();
  double lam=shv[0];
  for(int i=tid;i<ncols;i+=512) Kd[i*LDK+i]+=lam;
  __syncthreads();
  for(int j=0;j<ncols;j++){
    double d=Kd[j*LDK+j];
    if(!(d>lam*0.25)) d=lam*0.25;
    double invd=1.0/d;
    if(tid==0) Kd[j*LDK+j]=d;
    int w=ncols-1-j;
    for(int e=tid;e<w*w;e+=512){
      int i2=j+1+e/w, k2=j+1+e%w;
      if(k2>=i2) Kd[i2*LDK+k2]-=Kd[j*LDK+i2]*Kd[j*LDK+k2]*invd;
    }
    __syncthreads();
  }
  for(int i=tid;i<ncols;i+=512) Yt[i]=1.0/sqrt(Kd[i*LDK+i]);
  __syncthreads();
  for(int e=tid;e<n2;e+=512){
    int i=e/ncols, k=e%ncols;
    if(k>=i) Kd[i*LDK+k]*=Yt[i];
  }
  __syncthreads();
  if(tid<ncols){
    int j=tid;
    Ri[j*66+j]=1.0/Kd[j*LDK+j];
    for(int i=j-1;i>=0;i--){
      double s=0.0;
      for(int k=i+1;k<=j;k++) s+=Kd[i*LDK+k]*Ri[k*66+j];
      Ri[i*66+j]=-s/Kd[i*LDK+i];
    }
  }
  __syncthreads();
  {
    int j=tid%ncols, rg=tid/ncols;   // groups=512/ncols, 2 rows/thread
    for(int b=0;b<nblk;b++){
      for(int e=tid;e<1024;e+=512) Yt[e]=Yg[b*1024+e];
      __syncthreads();
      double xr[2];
      #pragma unroll
      for(int r4=0;r4<2;r4++){
        int r=rg*2+r4;
        double acc=0.0;
        for(int k=0;k<=j;k++) acc+=Yt[r*ncols+k]*Ri[k*66+j];
        xr[r4]=acc;
      }
      __syncthreads();
      #pragma unroll
      for(int r4=0;r4<2;r4++){
        int r=rg*2+r4;
        Yg[(size_t)b*1024 + r*ncols + j]=xr[r4];
      }
    }
  }
  __syncthreads();
}

// subspace path (ru==256): S4 precomputed by batched GEMM. Schedule:
// Ya=S4*Omega, QR2, 4x{Ya=S4*Ya; QR1}, QR, Ritz with S*Ya. (= S^20 filter,
// same as R4; QR cadence stretched S^2->S^4, shifted-CholQR handles junk.)
__global__ __launch_bounds__(512,1)
void k_eig_sub(double* ws, int Soff, int S4off, int MPoff, int l, int keep,
               int newoff, int Coff){
  const int RU=256;
  int tid=threadIdx.x;
  double* base=ws+(size_t)blockIdx.z*SAMP_J;
  const double* S =base+Soff;
  const double* S4=base+S4off;
  const double* MP=base+MPoff;
  double* Ya=base+O_Y;
  double* Yb=base+O_Y2;
  double* V =base+O_V;
  double* C =base+Coff;
  double* NM=base+newoff;
  __shared__ double Kd[64*LDK];    // 33.3 KB
  __shared__ double Ri[64*66];     // 33.8 KB
  __shared__ float  Wf[64*LDK];    // 16.6 KB
  __shared__ double Yt[1024];      // 8 KB
  __shared__ double red[516];
  __shared__ unsigned long long om[256];
  __shared__ double csC[32], csS[32];
  __shared__ int csP[32], csQ[32];
  __shared__ double evals[64]; __shared__ int idxs[64];

  // Omega sign table
  for(int c2=tid;c2<256;c2+=512){
    unsigned long long mask=0ull;
    for(int j=0;j<64;j++){
      unsigned h=(unsigned)(c2*1103515245u)^(unsigned)((j+1)*2654435761u);
      h^=h>>13; h*=0x9E3779B1u;
      mask |= ((unsigned long long)((h>>16)&1u))<<j;
    }
    om[c2]=mask;
  }
  __syncthreads();

  // Ya = S4 * Omega
  for(int e=tid;e<RU*64;e+=512){
    int i=e>>6, j=e&63;
    const double* Si=S4+(size_t)i*RU;
    double acc=0.0;
    for(int c2=0;c2<RU;c2++)
      acc += ((om[c2]>>j)&1ull)? Si[c2] : -Si[c2];
    Ya[e]=acc;
  }
  __syncthreads();
  dev_cholqr(Ya,64,Kd,Yt,Ri,red+512,tid);
  dev_cholqr(Ya,64,Kd,Yt,Ri,red+512,tid);
  for(int it=0;it<4;it++){
    dev_smul(S4,Ya,Yb,Yt,tid);
    double* t=Ya; Ya=Yb; Yb=t;
    dev_cholqr(Ya,64,Kd,Yt,Ri,red+512,tid);
  }
  dev_cholqr(Ya,64,Kd,Yt,Ri,red+512,tid);   // tighten pre-Ritz
  dev_smul(S,Ya,Yb,Yt,tid);                 // Yb = S*Ya (unorthogonalized)

  // Ritz: K = Ya^T Yb
  for(int e=tid;e<4096;e+=512){ int a=e>>6,c=e&63; Kd[a*LDK+c]=0.0; }
  for(int b=0;b<32;b++){
    __syncthreads();
    { int e=tid; Yt[e]=Ya[b*512+e]; }
    { int e=tid; Yt[512+e]=Yb[b*512+e]; }
    __syncthreads();
    for(int i=0;i<8;i++){
      int idx=tid*8+i; int a=idx>>6, c=idx&63;
      double acc=Kd[a*LDK+c];
      for(int r=0;r<8;r++) acc+=Yt[r*64+a]*Yt[512+r*64+c];
      Kd[a*LDK+c]=acc;
    }
  }
  __syncthreads();
  for(int e=tid;e<4096;e+=512){
    int a=e>>6,c=e&63;
    if(a<c){ double m=0.5*(Kd[a*LDK+c]+Kd[c*LDK+a]); Kd[a*LDK+c]=m; Kd[c*LDK+a]=m; }
  }
  __syncthreads();
  for(int e=tid;e<4096;e+=512){ int a=e>>6,c=e&63; Wf[a*LDK+c]=(a==c)?1.f:0.f; }
  __syncthreads();
  dev_jacobi(Kd,Wf,64,tid,6,csC,csS,csP,csQ);
  dev_select(Kd,64,keep,tid,evals,idxs);
  // V = Ya * W[:,sel]
  for(int e=tid;e<RU*keep;e+=512){
    int i=e/keep, j=e%keep; int vj=idxs[j];
    const double* Yr=Ya+(size_t)i*64;
    double acc=0.0;
    for(int t=0;t<64;t++) acc+=Yr[t]*(double)Wf[t*LDK+vj];
    V[e]=acc;
  }
  __syncthreads();
  dev_cholqr(V,keep,Kd,Yt,Ri,red+512,tid);   // f64 exact-projector fix
  for(int e=tid;e<keep*RU;e+=512){
    int j=e/RU, col=e%RU;
    NM[e]=V[(size_t)col*keep+j];
  }
  for(int e=tid;e<l*keep;e+=512){
    int i=e/keep, j=e%keep;
    const double* Mi=MP+(size_t)i*RU;
    double acc=0.0;
    for(int col=0;col<RU;col++) acc+=Mi[col]*V[(size_t)col*keep+j];
    C[e]=acc;
  }
}

// ---------------------------------------------------------------------------
__global__ void k_copy(double* ws){
  double* base=ws+(size_t)blockIdx.z*SAMP_J;
  for(int e=blockIdx.x*blockDim.x+threadIdx.x;e<65536;e+=gridDim.x*blockDim.x)
    base[O_CUR+e]=base[O_NEW+e];
}

__global__ __launch_bounds__(256)
void k_final(double* ws, float* out, int s0){
  int z=blockIdx.z, tid=threadIdx.x;
  const double* bot=ws+(size_t)(2*z)*SAMP_J+O_CUR;
  const double* top=ws+(size_t)(2*z+1)*SAMP_J+O_CUR;
  __shared__ double v[1024], v2[1024];
  __shared__ float w[8192];
  const int Bf[9]={1,8,32,32,32,32,32,8,1};
  if(tid==0) v[0]=1.0;
  __syncthreads();
  for(int y=0;y<8;y++){
    int a=Bf[y], b=Bf[y+1];
    const double* By=bot+y*8192;
    const double* Ty=top+y*8192;
    for(int e=tid;e<a*b*8;e+=256){
      int k2=e&7; int bb=(e>>3)%b; int cc=e/(8*b);
      double acc=0.0;
      for(int aa=0;aa<a;aa++) acc+=v[aa*a+cc]*By[(aa*b+bb)*8+k2];
      w[(cc*b+bb)*8+k2]=(float)acc;
    }
    __syncthreads();
    for(int e=tid;e<b*b;e+=256){
      int dd=e%b; int bb=e/b;
      double acc=0.0;
      for(int cc=0;cc<a;cc++)
        for(int k2=0;k2<8;k2++)
          acc+=(double)w[(cc*b+bb)*8+k2]*Ty[(cc*b+dd)*8+k2];
      v2[bb*b+dd]=acc;
    }
    __syncthreads();
    for(int e=tid;e<b*b;e+=256) v[e]=v2[e];
    __syncthreads();
  }
  if(tid==0) out[s0+z]=(float)v[0];
}

// ---------------------------------------------------------------------------
static void run_compress_dual(double* ws, const float* peps, const int* x,
                              int s0, int ns, int xib, int xit, bool first,
                              hipStream_t stream){
  int njobs=2*ns;
  int Bin[9]; Bin[0]=1; Bin[8]=1;
  for(int i=1;i<8;i++) Bin[i]= first?8:((i==1||i==7)?8:32);
  int lraw[8], rraw[8];
  for(int y=0;y<8;y++){ lraw[y]=Bin[y]*((y>0)?8:1); rraw[y]=Bin[y+1]*((y<7)?8:1); }
  int kch[8];
  { int kp=1;
    for(int y=0;y<8;y++){ int n=(y<7)?Bin[y+1]*8:1; kch[y]=imin_(kp*8,n); kp=kch[y]; } }
  int keep[8];
  keep[7]=imin_(32, imin_(kch[6], 8));
  for(int y=6;y>=1;y--) keep[y]=imin_(32, imin_(kch[y-1], keep[y+1]*8));

  // forward: G^(1..7)
  for(int y=0;y<7;y++){
    k_absorb<<<dim3(Bin[y+1],1,njobs),256,0,stream>>>(ws,peps,x,s0,xib,xit,y,Bin[y],Bin[y+1]);
    int l=lraw[y], r8=rraw[y]*8;
    k_mmGT<<<dim3((l+15)/16,(r8+15)/16,njobs),dim3(16,16),0,stream>>>(
        ws,O_GSB+goff[y],O_TF,O_H2F,l,l,r8);
    k_gacc2<<<dim3(rraw[y]/16,rraw[y]/16,njobs),dim3(16,16),0,stream>>>(
        ws,O_H2F,O_TF,O_GSB+goff[y+1],l,rraw[y]);
    k_gscale<<<dim3(1,1,njobs),256,0,stream>>>(ws,O_GSB+goff[y+1],rraw[y]);
  }
  // backward
  for(int y=7;y>=1;y--){
    k_absorb<<<dim3(Bin[y+1],1,njobs),256,0,stream>>>(ws,peps,x,s0,xib,xit,y,Bin[y],Bin[y+1]);
    int ru=(y==7)?8:keep[y+1]*8;
    if(y==7) k_t2mp<<<dim3(2,1,njobs),256,0,stream>>>(ws,lraw[7]*8);
    else     k_mp<<<dim3(lraw[y],1,njobs),256,0,stream>>>(ws,O_TF,O_C,O_MP,rraw[y],keep[y+1]);
    int l=lraw[y];
    k_mm<<<dim3((l+15)/16,(ru+15)/16,njobs),dim3(16,16),0,stream>>>(
        ws,O_GSB+goff[y],O_MP,O_H,l,l,ru);
    k_mm_tn<<<dim3((ru+15)/16,(ru+15)/16,njobs),dim3(16,16),0,stream>>>(
        ws,O_MP,O_H,O_S,ru,l,ru);
    if(ru<=64){
      k_eig_direct<<<dim3(1,1,njobs),256,0,stream>>>(ws,O_S,O_MP,l,ru,keep[y],
                    O_NEW+y*8192,O_C);
    } else {
      // S2 = S*S into O_H (dead), S4 = S2*S2 into O_S4 (dead G^(6) slot)
      k_mm<<<dim3(16,16,njobs),dim3(16,16),0,stream>>>(ws,O_S,O_S,O_H,256,256,256);
      k_mm<<<dim3(16,16,njobs),dim3(16,16),0,stream>>>(ws,O_H,O_H,O_S4,256,256,256);
      k_eig_sub<<<dim3(1,1,njobs),512,0,stream>>>(ws,O_S,O_S4,O_MP,l,keep[y],
                    O_NEW+y*8192,O_C);
    }
  }
  // site 0
  k_absorb<<<dim3(Bin[1],1,njobs),256,0,stream>>>(ws,peps,x,s0,xib,xit,0,1,Bin[1]);
  k_mp<<<dim3(1,1,njobs),256,0,stream>>>(ws,O_TF,O_C,O_NEW+0,rraw[0],keep[1]);
  k_copy<<<dim3(32,1,njobs),256,0,stream>>>(ws);
}

extern "C" void kernel_launch(void* const* d_in, const int* in_sizes, int n_in,
                              void* d_out, int out_size, void* d_ws, size_t ws_size,
                              hipStream_t stream){
  const int*   x    = (const int*)d_in[0];     // (16,64) int32
  const float* peps = (const float*)d_in[1];   // (8,8,8,8,8,8,2) f32
  float* out = (float*)d_out;                  // 16 f32
  double* ws = (double*)d_ws;
  size_t samp_bytes = (size_t)2*SAMP_J*sizeof(double);
  int max_chunk=(int)(ws_size/samp_bytes);
  if(max_chunk<1) max_chunk=1;
  if(max_chunk>16) max_chunk=16;
  for(int s0=0;s0<16;s0+=max_chunk){
    int ns=imin_(max_chunk,16-s0);
    int njobs=2*ns;
    k_init_row<<<dim3(8,1,njobs),64,0,stream>>>(ws,peps,x,s0);
    run_compress_dual(ws,peps,x,s0,ns,1,6,true ,stream);
    run_compress_dual(ws,peps,x,s0,ns,2,5,false,stream);
    run_compress_dual(ws,peps,x,s0,ns,3,4,false,stream);
    k_final<<<dim3(1,1,ns),256,0,stream>>>(ws,out,s0);
  }
}